// Round 4
// baseline (7452.657 us; speedup 1.0000x reference)
//
#include <hip/hip_runtime.h>

#define DD 512
#define NBLK 24
#define BLK (64 * DD)            // one 64-row arm block (floats)
#define WT_SLOT 524288           // shorts per transposed matrix (512*512*2)
#define NWG 256                  // fused-kernel grid

typedef short s16x8 __attribute__((ext_vector_type(8)));
typedef float f32x4 __attribute__((ext_vector_type(4)));

union FragU { s16x8 s; __bf16 h[8]; };

__device__ __forceinline__ f32x4 mfma16(s16x8 a, s16x8 b, f32x4 c) {
  return __builtin_amdgcn_mfma_f32_16x16x32_bf16(a, b, c, 0, 0, 0);
}

__device__ __forceinline__ void bsplit(float v, __bf16& hi, __bf16& lo) {
  hi = (__bf16)v;
  lo = (__bf16)(v - (float)hi);
}

// Device-scope barrier: monotonic counter, one atomic per wg, agent-scope
// release/acquire (emits L2 writeback/invalidate for cross-XCD visibility).
__device__ __forceinline__ void gbar(unsigned int* cnt, unsigned int target) {
  __syncthreads();
  if (threadIdx.x == 0) {
    __hip_atomic_fetch_add(cnt, 1u, __ATOMIC_ACQ_REL, __HIP_MEMORY_SCOPE_AGENT);
    while (__hip_atomic_load(cnt, __ATOMIC_ACQUIRE, __HIP_MEMORY_SCOPE_AGENT) < target)
      __builtin_amdgcn_s_sleep(2);
  }
  __syncthreads();
}

__constant__ int c_wmap[7] = {0, 1, 2, 7, 8, 9, 10};

// ---------------------------------------------------------------------------
// Gather GEMM core (fallback path + k_p1a). 256 threads, 64x64 tile.
// ---------------------------------------------------------------------------
template<int AMODE, bool RESID>
__device__ __forceinline__ void gemm64_core(
    const float* __restrict__ Abase, int rshift, long sOuter,
    const float* __restrict__ Wf,
    const float* __restrict__ bias,
    const float* __restrict__ lng, const float* __restrict__ lnb,
    const float* __restrict__ resid,
    float* __restrict__ outF,
    int n0)
{
  const int tid  = threadIdx.x;
  const int wave = tid >> 6;
  const int lane = tid & 63;
  const int l15  = lane & 15;
  const int lq   = lane >> 4;

  const int rowA = wave * 16 + l15;
  const float* Arow = Abase + (long)(rowA >> rshift) * sOuter
                            + (long)(rowA & ((1 << rshift) - 1)) * DD;

  float mu = 0.f, rstd = 0.f;
  if constexpr (AMODE == 2) {
    float s = 0.f, ss = 0.f;
    const float* p = Arow + lq * 128;
    #pragma unroll
    for (int k = 0; k < 128; k += 4) {
      float4 v = *reinterpret_cast<const float4*>(p + k);
      s  += v.x + v.y + v.z + v.w;
      ss += v.x * v.x + v.y * v.y + v.z * v.z + v.w * v.w;
    }
    s += __shfl_xor(s, 16); ss += __shfl_xor(ss, 16);
    s += __shfl_xor(s, 32); ss += __shfl_xor(ss, 32);
    mu = s * (1.f / 512.f);
    float var = ss * (1.f / 512.f) - mu * mu;
    rstd = rsqrtf(var + 1e-5f);
  }

  f32x4 acc[4] = {};

  for (int ks = 0; ks < 16; ++ks) {
    const int k0 = ks * 32 + lq * 8;
    FragU ahi, alo;
    {
      float4 v0 = *reinterpret_cast<const float4*>(Arow + k0);
      float4 v1 = *reinterpret_cast<const float4*>(Arow + k0 + 4);
      float t0[8] = {v0.x, v0.y, v0.z, v0.w, v1.x, v1.y, v1.z, v1.w};
      if constexpr (AMODE == 2) {
        float4 g0 = *reinterpret_cast<const float4*>(lng + k0);
        float4 g1 = *reinterpret_cast<const float4*>(lng + k0 + 4);
        float4 c0 = *reinterpret_cast<const float4*>(lnb + k0);
        float4 c1 = *reinterpret_cast<const float4*>(lnb + k0 + 4);
        float gg[8] = {g0.x, g0.y, g0.z, g0.w, g1.x, g1.y, g1.z, g1.w};
        float cc[8] = {c0.x, c0.y, c0.z, c0.w, c1.x, c1.y, c1.z, c1.w};
        #pragma unroll
        for (int e = 0; e < 8; ++e) {
          float v = (t0[e] - mu) * rstd * gg[e] + cc[e];
          bsplit(v, ahi.h[e], alo.h[e]);
        }
      } else {
        #pragma unroll
        for (int e = 0; e < 8; ++e) {
          float v = t0[e];
          if constexpr (AMODE == 1) v = fmaxf(v, 0.f);
          bsplit(v, ahi.h[e], alo.h[e]);
        }
      }
    }
    const float* wp = Wf + (long)k0 * DD + n0 + l15;
    #pragma unroll
    for (int j = 0; j < 4; ++j) {
      FragU bhi, blo;
      #pragma unroll
      for (int e = 0; e < 8; ++e) {
        float w = wp[(long)e * DD + j * 16];
        bsplit(w, bhi.h[e], blo.h[e]);
      }
      acc[j] = mfma16(ahi.s, bhi.s, acc[j]);
      acc[j] = mfma16(ahi.s, blo.s, acc[j]);
      acc[j] = mfma16(alo.s, bhi.s, acc[j]);
    }
  }

  const int mbase = wave * 16 + lq * 4;
  #pragma unroll
  for (int j = 0; j < 4; ++j) {
    const int n = n0 + j * 16 + l15;
    const float bv = bias[n];
    #pragma unroll
    for (int r = 0; r < 4; ++r) {
      const int m = mbase + r;
      float v = acc[j][r] + bv;
      if constexpr (RESID) v += fmaxf(resid[(long)m * DD + n], 0.f);
      outF[(long)m * DD + n] = v;
    }
  }
}

// ---------------------------------------------------------------------------
// Transposed-weight core, 512 threads (8 waves): 64 rows x 32 cols tile.
// wave = (nh = wave>>2 col-half, mq = wave&3 row-quad). K-range [ks0,ks1).
// ---------------------------------------------------------------------------
template<int AMODE, bool A2P>
__device__ __forceinline__ void gemmT512(
    const float* __restrict__ A1, const float* __restrict__ A2,
    const unsigned short* __restrict__ Wt,   // slot base
    const float* __restrict__ bias, int addBias,
    const float* __restrict__ lng, const float* __restrict__ lnb,
    const float* __restrict__ r1, const float* __restrict__ r2,
    float* __restrict__ outF, int n0, int ks0, int ks1)
{
  const int tid  = threadIdx.x;
  const int wave = tid >> 6;
  const int mq   = wave & 3;
  const int nh   = wave >> 2;
  const int lane = tid & 63;
  const int l15  = lane & 15;
  const int lq   = lane >> 4;

  const int rowA = mq * 16 + l15;
  const float* A1row = A1 + (long)rowA * DD;
  const float* A2row = A2P ? (A2 + (long)rowA * DD) : nullptr;

  float mu = 0.f, rstd = 0.f;
  if constexpr (AMODE == 2) {
    float s = 0.f, ss = 0.f;
    const float* p1 = A1row + lq * 128;
    const float* p2 = A2P ? (A2row + lq * 128) : nullptr;
    #pragma unroll
    for (int k = 0; k < 128; k += 4) {
      float4 v = *reinterpret_cast<const float4*>(p1 + k);
      float vx = v.x, vy = v.y, vz = v.z, vw = v.w;
      if constexpr (A2P) {
        float4 u = *reinterpret_cast<const float4*>(p2 + k);
        vx += u.x; vy += u.y; vz += u.z; vw += u.w;
      }
      s  += vx + vy + vz + vw;
      ss += vx * vx + vy * vy + vz * vz + vw * vw;
    }
    s += __shfl_xor(s, 16); ss += __shfl_xor(ss, 16);
    s += __shfl_xor(s, 32); ss += __shfl_xor(ss, 32);
    mu = s * (1.f / 512.f);
    float var = ss * (1.f / 512.f) - mu * mu;
    rstd = rsqrtf(var + 1e-5f);
  }

  f32x4 acc = {};
  const long ngBase = (long)((n0 + nh * 16) >> 4) * 64;

  for (int ks = ks0; ks < ks1; ++ks) {
    const int k0 = ks * 32 + lq * 8;
    FragU ahi, alo;
    {
      float4 v0 = *reinterpret_cast<const float4*>(A1row + k0);
      float4 v1 = *reinterpret_cast<const float4*>(A1row + k0 + 4);
      float t0[8] = {v0.x, v0.y, v0.z, v0.w, v1.x, v1.y, v1.z, v1.w};
      if constexpr (A2P) {
        float4 u0 = *reinterpret_cast<const float4*>(A2row + k0);
        float4 u1 = *reinterpret_cast<const float4*>(A2row + k0 + 4);
        t0[0] += u0.x; t0[1] += u0.y; t0[2] += u0.z; t0[3] += u0.w;
        t0[4] += u1.x; t0[5] += u1.y; t0[6] += u1.z; t0[7] += u1.w;
      }
      if constexpr (AMODE == 2) {
        float4 g0 = *reinterpret_cast<const float4*>(lng + k0);
        float4 g1 = *reinterpret_cast<const float4*>(lng + k0 + 4);
        float4 c0 = *reinterpret_cast<const float4*>(lnb + k0);
        float4 c1 = *reinterpret_cast<const float4*>(lnb + k0 + 4);
        float gg[8] = {g0.x, g0.y, g0.z, g0.w, g1.x, g1.y, g1.z, g1.w};
        float cc[8] = {c0.x, c0.y, c0.z, c0.w, c1.x, c1.y, c1.z, c1.w};
        #pragma unroll
        for (int e = 0; e < 8; ++e) {
          float v = (t0[e] - mu) * rstd * gg[e] + cc[e];
          bsplit(v, ahi.h[e], alo.h[e]);
        }
      } else {
        #pragma unroll
        for (int e = 0; e < 8; ++e) {
          float v = t0[e];
          if constexpr (AMODE == 1) v = fmaxf(v, 0.f);
          bsplit(v, ahi.h[e], alo.h[e]);
        }
      }
    }
    const unsigned short* wp = Wt + ((ngBase + (ks * 4 + lq)) * 16 + l15) * 16;
    s16x8 bhi = *reinterpret_cast<const s16x8*>(wp);
    s16x8 blo = *reinterpret_cast<const s16x8*>(wp + 8);
    acc = mfma16(ahi.s, bhi, acc);
    acc = mfma16(ahi.s, blo, acc);
    acc = mfma16(alo.s, bhi, acc);
  }

  const int mbase = mq * 16 + lq * 4;
  const int n = n0 + nh * 16 + l15;
  const float bv = addBias ? bias[n] : 0.f;
  #pragma unroll
  for (int r = 0; r < 4; ++r) {
    const int m = mbase + r;
    float v = acc[r] + bv;
    if (r1) {
      float rv = r1[(long)m * DD + n];
      if (r2) rv += r2[(long)m * DD + n];
      v += fmaxf(rv, 0.f);
    }
    outF[(long)m * DD + n] = v;
  }
}

// ---------------------------------------------------------------------------
// Phase-0: weight transpose (unchanged from round 3)
// ---------------------------------------------------------------------------
__global__ __launch_bounds__(256) void k_wt(
    const float* __restrict__ WL, const float* __restrict__ WR,
    unsigned short* __restrict__ Wt)
{
  const int bx = blockIdx.x;
  const int ng = bx & 31, slot = bx >> 5;
  const int wi7 = slot % 7, nb2 = slot / 7;
  const int arm = nb2 & 1, nb = nb2 >> 1;
  const float* Wsrc = (arm ? WR : WL) + (long)(nb * 11 + c_wmap[wi7]) * DD * DD;

  const int t = threadIdx.x;
  const int k8 = t >> 2, lbase = (t & 3) * 4;

  unsigned short hi[4][8], lo[4][8];
  #pragma unroll
  for (int e = 0; e < 8; ++e) {
    float4 v = *reinterpret_cast<const float4*>(
        Wsrc + (long)(k8 * 8 + e) * DD + ng * 16 + lbase);
    float vv[4] = {v.x, v.y, v.z, v.w};
    #pragma unroll
    for (int c = 0; c < 4; ++c) {
      __bf16 h, l;
      bsplit(vv[c], h, l);
      union { __bf16 b; unsigned short u; } ch, cl; ch.b = h; cl.b = l;
      hi[c][e] = ch.u; lo[c][e] = cl.u;
    }
  }
  unsigned short* dst = Wt + (long)slot * WT_SLOT
                      + ((long)(ng * 64 + k8) * 16 + lbase) * 16;
  #pragma unroll
  for (int c = 0; c < 4; ++c) {
    s16x8 a, b;
    #pragma unroll
    for (int e = 0; e < 8; ++e) { ((short*)&a)[e] = hi[c][e]; ((short*)&b)[e] = lo[c][e]; }
    *reinterpret_cast<s16x8*>(dst + c * 16)     = a;
    *reinterpret_cast<s16x8*>(dst + c * 16 + 8) = b;
  }
}

// ---------------------------------------------------------------------------
// Phase-1: kt/vt (unchanged)
// ---------------------------------------------------------------------------
#define LDSW 40

__global__ __launch_bounds__(256) void k_p1t(
    const float* __restrict__ ahs,
    const float* __restrict__ WL, const float* __restrict__ WR,
    const float* __restrict__ bL, const float* __restrict__ bR,
    float* __restrict__ kvt)
{
  __shared__ __align__(16) unsigned short Ab[2][64 * LDSW];
  __shared__ __align__(16) unsigned short Wb[4][2][64 * LDSW];

  const int bx = blockIdx.x;
  const int ntile = bx & 7, mtile = (bx >> 3) & 7, nb = bx >> 6;
  const int n0 = ntile * 64;

  const float* Abase = ahs + (long)(mtile * 25 + nb + 1) * 80 * DD;
  const float* Wp[4];
  const float* bp[4];
  #pragma unroll
  for (int o = 0; o < 4; ++o) {
    const int arm = o >> 1, kv = o & 1;
    Wp[o] = (arm ? WR : WL) + (long)(nb * 11 + 3 + kv) * DD * DD;
    bp[o] = (arm ? bR : bL) + (long)(nb * 11 + 3 + kv) * DD;
  }

  const int tid  = threadIdx.x;
  const int srow = tid >> 2;
  const int skq  = (tid & 3) * 8;
  const int wave = tid >> 6, lane = tid & 63, l15 = lane & 15, lq = lane >> 4;

  f32x4 acc[4][4] = {};
  float aR[8];
  float wRg[4][8];

  auto loadStage = [&](int kbase) {
    const float* ap = Abase + (long)srow * DD + kbase + skq;
    float4 v0 = *reinterpret_cast<const float4*>(ap);
    float4 v1 = *reinterpret_cast<const float4*>(ap + 4);
    aR[0] = v0.x; aR[1] = v0.y; aR[2] = v0.z; aR[3] = v0.w;
    aR[4] = v1.x; aR[5] = v1.y; aR[6] = v1.z; aR[7] = v1.w;
    #pragma unroll
    for (int o = 0; o < 4; ++o) {
      #pragma unroll
      for (int e = 0; e < 8; ++e)
        wRg[o][e] = Wp[o][(long)(kbase + skq + e) * DD + n0 + srow];
    }
  };

  loadStage(0);
  for (int s = 0; s < 16; ++s) {
    __syncthreads();
    {
      FragU uh, ul;
      #pragma unroll
      for (int e = 0; e < 8; ++e) bsplit(aR[e], uh.h[e], ul.h[e]);
      *reinterpret_cast<s16x8*>(&Ab[0][srow * LDSW + skq]) = uh.s;
      *reinterpret_cast<s16x8*>(&Ab[1][srow * LDSW + skq]) = ul.s;
      #pragma unroll
      for (int o = 0; o < 4; ++o) {
        FragU wh, wl;
        #pragma unroll
        for (int e = 0; e < 8; ++e) bsplit(wRg[o][e], wh.h[e], wl.h[e]);
        *reinterpret_cast<s16x8*>(&Wb[o][0][srow * LDSW + skq]) = wh.s;
        *reinterpret_cast<s16x8*>(&Wb[o][1][srow * LDSW + skq]) = wl.s;
      }
    }
    __syncthreads();
    if (s < 15) loadStage((s + 1) * 32);
    s16x8 ahi = *reinterpret_cast<const s16x8*>(&Ab[0][(wave * 16 + l15) * LDSW + lq * 8]);
    s16x8 alo = *reinterpret_cast<const s16x8*>(&Ab[1][(wave * 16 + l15) * LDSW + lq * 8]);
    #pragma unroll
    for (int o = 0; o < 4; ++o) {
      #pragma unroll
      for (int j = 0; j < 4; ++j) {
        s16x8 bhi = *reinterpret_cast<const s16x8*>(&Wb[o][0][(j * 16 + l15) * LDSW + lq * 8]);
        s16x8 blo = *reinterpret_cast<const s16x8*>(&Wb[o][1][(j * 16 + l15) * LDSW + lq * 8]);
        acc[o][j] = mfma16(ahi, bhi, acc[o][j]);
        acc[o][j] = mfma16(ahi, blo, acc[o][j]);
        acc[o][j] = mfma16(alo, bhi, acc[o][j]);
      }
    }
  }

  const int mbase = mtile * 64 + wave * 16 + lq * 4;
  #pragma unroll
  for (int o = 0; o < 4; ++o) {
    float* outb = kvt + (long)(nb * 4 + o) * 512 * DD;
    #pragma unroll
    for (int j = 0; j < 4; ++j) {
      const int n = n0 + j * 16 + l15;
      const float bv = bp[o][n];
      #pragma unroll
      for (int r = 0; r < 4; ++r)
        outb[(long)(mbase + r) * DD + n] = acc[o][j][r] + bv;
    }
  }
}

// Phase-1: ka/va (gather core)
__global__ __launch_bounds__(256) void k_p1a(
    const float* __restrict__ ahs,
    const float* __restrict__ WL, const float* __restrict__ WR,
    const float* __restrict__ bL, const float* __restrict__ bR,
    float* __restrict__ kva)
{
  const int bx = blockIdx.x;
  const int ntile = bx & 7, kv = (bx >> 3) & 1, arm = (bx >> 4) & 1, nb = bx >> 5;
  const float* Abase = ahs + ((long)(nb + 1) * 80 + 64 + arm * 8) * DD;
  const float* W    = (arm ? WR : WL) + (long)(nb * 11 + 5 + kv) * DD * DD;
  const float* bias = (arm ? bR : bL) + (long)(nb * 11 + 5 + kv) * DD;
  float* out = kva + (long)(nb * 4 + arm * 2 + kv) * 64 * DD;
  gemm64_core<0, false>(Abase, 3, (long)25 * 80 * DD, W, bias,
                        nullptr, nullptr, nullptr, out, ntile * 64);
}

// ---------------------------------------------------------------------------
// FUSED sequential scan: all 24 blocks + final head in ONE kernel.
// 256 wgs x 512 threads; software global barrier between phases.
// ---------------------------------------------------------------------------
__global__ __launch_bounds__(512, 4) void k_fused(
    float* __restrict__ xp, float* __restrict__ qkvb,
    float* __restrict__ attno, float* __restrict__ yp,
    const float* __restrict__ kvt, const float* __restrict__ kva,
    const unsigned short* __restrict__ Wt,
    const float* __restrict__ bL, const float* __restrict__ bR,
    const float* __restrict__ lngL, const float* __restrict__ lnbL,
    const float* __restrict__ lngR, const float* __restrict__ lnbR,
    const float* __restrict__ gating,
    const float* __restrict__ ropeC, const float* __restrict__ ropeS,
    const float* __restrict__ fgL, const float* __restrict__ fbL,
    const float* __restrict__ fgR, const float* __restrict__ fbR,
    const float* __restrict__ fwL, const float* __restrict__ fcbL,
    const float* __restrict__ fwR, const float* __restrict__ fcbR,
    float* __restrict__ out, unsigned int* __restrict__ cnt)
{
  __shared__ float kb[88 * 65];
  __shared__ float vb[88 * 65];
  __shared__ float qb[8 * 65];
  __shared__ float pb[8 * 89];

  const int wg  = blockIdx.x;
  const int tid = threadIdx.x;
  unsigned int bi = 0;

  for (int nb = 0; nb < NBLK; ++nb) {
    // ---------------- QKV: 160 tiles of 64x32 ----------------
    if (wg < 160) {
      const int arm = wg / 80;
      const int rem = wg - arm * 80;
      const int wi = rem >> 4, nt = rem & 15;
      const int sel = (wi < 3) ? arm : (1 - arm);
      gemmT512<1, true>(
          xp + (long)sel * BLK, xp + (long)(2 + sel) * BLK,
          Wt + (((long)nb * 2 + arm) * 7 + wi) * WT_SLOT,
          (arm ? bR : bL) + ((long)nb * 11 + c_wmap[wi]) * DD, 1,
          nullptr, nullptr, nullptr, nullptr,
          qkvb + ((long)arm * 5 + wi) * BLK, nt * 32, 0, 16);
    }
    gbar(cnt, ++bi * NWG);

    // ---------------- ATTN: 128 wgs (arm,b,h) ----------------
    if (wg < 128) {
      const int h = wg & 7, b = (wg >> 3) & 7, arm = wg >> 6;
      const float g = tanhf(gating[nb]);

      {
        const int p = tid >> 6, d = tid & 63;
        const float* qrow = qkvb + ((long)(arm * 5 + 0) * 64 + b * 8 + p) * DD + h * 64;
        float v = qrow[d], vp = qrow[d ^ 1];
        float c = ropeC[p * 64 + d], s = ropeS[p * 64 + d];
        qb[p * 65 + d] = v * c + ((d & 1) ? vp : -vp) * s;
      }
      for (int idx = tid; idx < 88 * 64; idx += 512) {
        const int j = idx >> 6, d = idx & 63;
        float kvval, vvval;
        if (j < 8) {
          const float* krow = qkvb + ((long)(arm * 5 + 1) * 64 + b * 8 + j) * DD + h * 64;
          float v = krow[d], vp = krow[d ^ 1];
          float c = ropeC[j * 64 + d], s = ropeS[j * 64 + d];
          kvval = v * c + ((d & 1) ? vp : -vp) * s;
          vvval = qkvb[((long)(arm * 5 + 2) * 64 + b * 8 + j) * DD + h * 64 + d];
        } else if (j < 16) {
          const int t = j - 8;
          kvval = kva[((long)(nb * 4 + arm * 2 + 0) * 64 + b * 8 + t) * DD + h * 64 + d];
          vvval = kva[((long)(nb * 4 + arm * 2 + 1) * 64 + b * 8 + t) * DD + h * 64 + d];
        } else if (j < 80) {
          const int t = j - 16;
          kvval = g * kvt[((long)(nb * 4 + arm * 2 + 0) * 512 + b * 64 + t) * DD + h * 64 + d];
          vvval = kvt[((long)(nb * 4 + arm * 2 + 1) * 512 + b * 64 + t) * DD + h * 64 + d];
        } else {
          const int t = j - 80;
          const float* krow = qkvb + ((long)(arm * 5 + 3) * 64 + b * 8 + t) * DD + h * 64;
          float v = krow[d], vp = krow[d ^ 1];
          float c = ropeC[t * 64 + d], s = ropeS[t * 64 + d];
          kvval = v * c + ((d & 1) ? vp : -vp) * s;
          vvval = qkvb[((long)(arm * 5 + 4) * 64 + b * 8 + t) * DD + h * 64 + d];
        }
        kb[j * 65 + d] = kvval;
        vb[j * 65 + d] = vvval;
      }
      __syncthreads();

      const int p = tid >> 6, lane = tid & 63;
      float s0 = 0.f, s1 = 0.f;
      const int j2 = 64 + ((lane < 24) ? lane : 0);
      #pragma unroll 8
      for (int d = 0; d < 64; ++d) {
        const float q = qb[p * 65 + d];
        s0 += q * kb[lane * 65 + d];
        s1 += q * kb[j2 * 65 + d];
      }
      s0 *= 0.125f; s1 *= 0.125f;
      float m = (lane < 24) ? fmaxf(s0, s1) : s0;
      #pragma unroll
      for (int off = 1; off < 64; off <<= 1) m = fmaxf(m, __shfl_xor(m, off));
      const float e0 = __expf(s0 - m);
      const float e1 = (lane < 24) ? __expf(s1 - m) : 0.f;
      float sum = e0 + e1;
      #pragma unroll
      for (int off = 1; off < 64; off <<= 1) sum += __shfl_xor(sum, off);
      const float inv = 1.f / sum;
      pb[p * 89 + lane] = e0 * inv;
      if (lane < 24) pb[p * 89 + 64 + lane] = e1 * inv;
      __syncthreads();

      float acc = 0.f;
      #pragma unroll 8
      for (int j = 0; j < 88; ++j) acc += pb[p * 89 + j] * vb[j * 65 + lane];
      attno[((long)arm * 64 + b * 8 + p) * DD + h * 64 + lane] = acc;
    }
    gbar(cnt, ++bi * NWG);

    // ---------------- PROJ: 64 wgs (arm,kh,nt32), K-split 2 ----------------
    if (wg < 64) {
      const int arm = wg >> 5, kh = (wg >> 4) & 1, nt = wg & 15;
      gemmT512<0, false>(
          attno + (long)arm * BLK, nullptr,
          Wt + (((long)nb * 2 + arm) * 7 + 5) * WT_SLOT,
          (arm ? bR : bL) + ((long)nb * 11 + 9) * DD, kh == 0,
          nullptr, nullptr,
          kh == 0 ? xp + (long)arm * BLK : nullptr,
          kh == 0 ? xp + (long)(2 + arm) * BLK : nullptr,
          yp + (long)(kh * 2 + arm) * BLK, nt * 32, kh * 8, kh * 8 + 8);
    }
    gbar(cnt, ++bi * NWG);

    // ---------------- FFN: 64 wgs ----------------
    if (wg < 64) {
      const int arm = wg >> 5, kh = (wg >> 4) & 1, nt = wg & 15;
      gemmT512<2, true>(
          yp + (long)arm * BLK, yp + (long)(2 + arm) * BLK,
          Wt + (((long)nb * 2 + arm) * 7 + 6) * WT_SLOT,
          (arm ? bR : bL) + ((long)nb * 11 + 10) * DD, kh == 0,
          (arm ? lngR : lngL) + (long)nb * DD, (arm ? lnbR : lnbL) + (long)nb * DD,
          nullptr, nullptr,
          xp + (long)(kh * 2 + arm) * BLK, nt * 32, kh * 8, kh * 8 + 8);
    }
    gbar(cnt, ++bi * NWG);
  }

  // ---------------- FINAL head: 16 wgs x 64 threads ----------------
  if (wg < 16 && tid < 64) {
    const int b = wg & 7, arm = wg >> 3;
    const int p = tid >> 3, k8 = tid & 7;
    const float* xr1 = xp + ((long)arm * 64 + b * 8 + p) * DD;
    const float* xr2 = xr1 + 2 * BLK;

    float s = 0.f, ss = 0.f;
    for (int k = k8 * 64; k < k8 * 64 + 64; k += 4) {
      float4 v = *reinterpret_cast<const float4*>(xr1 + k);
      float4 u = *reinterpret_cast<const float4*>(xr2 + k);
      float a0 = fmaxf(v.x + u.x, 0.f), a1 = fmaxf(v.y + u.y, 0.f);
      float a2 = fmaxf(v.z + u.z, 0.f), a3 = fmaxf(v.w + u.w, 0.f);
      s  += a0 + a1 + a2 + a3;
      ss += a0 * a0 + a1 * a1 + a2 * a2 + a3 * a3;
    }
    s += __shfl_xor(s, 1); ss += __shfl_xor(ss, 1);
    s += __shfl_xor(s, 2); ss += __shfl_xor(ss, 2);
    s += __shfl_xor(s, 4); ss += __shfl_xor(ss, 4);
    const float mu = s * (1.f / 512.f);
    const float var = ss * (1.f / 512.f) - mu * mu;
    const float rstd = rsqrtf(var + 1e-5f);

    const float* g   = arm ? fgR : fgL;
    const float* bb  = arm ? fbR : fbL;
    const float* fw  = arm ? fwR : fwL;
    const float* fcb = arm ? fcbR : fcbL;
    const int j = k8;
    if (j < 7) {
      float acc = 0.f;
      for (int k = 0; k < 512; ++k) {
        const float xv = fmaxf(xr1[k] + xr2[k], 0.f);
        const float xn = (xv - mu) * rstd * g[k] + bb[k];
        acc += xn * fw[k * 7 + j];
      }
      out[((long)(b * 8) + p) * 14 + arm * 7 + j] = acc + fcb[j];
    }
  }
}

// ---------------------------------------------------------------------------
// Fallback (gather path) kernels — only used when ws can't hold Wt
// ---------------------------------------------------------------------------
__global__ __launch_bounds__(256) void k_qkv_g(
    const float* __restrict__ x,
    const float* __restrict__ WL, const float* __restrict__ WR,
    const float* __restrict__ bL, const float* __restrict__ bR,
    float* __restrict__ qkv, int nb)
{
  const int bx = blockIdx.x;
  const int arm = bx / 40;
  const int rem = bx - arm * 40;
  const int wi = rem >> 3, ntile = rem & 7;
  const int w = (wi < 3) ? wi : wi + 4;
  const float* A    = x + (long)((wi < 3) ? arm : (1 - arm)) * BLK;
  const float* W    = (arm ? WR : WL) + (long)(nb * 11 + w) * DD * DD;
  const float* bias = (arm ? bR : bL) + (long)(nb * 11 + w) * DD;
  float* out = qkv + (long)(arm * 5 + wi) * BLK;
  gemm64_core<1, false>(A, 6, 0, W, bias, nullptr, nullptr, nullptr,
                        out, ntile * 64);
}

__global__ __launch_bounds__(256) void k_proj_g(
    const float* __restrict__ attno,
    const float* __restrict__ WL, const float* __restrict__ WR,
    const float* __restrict__ bL, const float* __restrict__ bR,
    const float* __restrict__ x, float* __restrict__ y, int nb)
{
  const int bx = blockIdx.x;
  const int arm = bx >> 3, ntile = bx & 7;
  const float* A    = attno + (long)arm * BLK;
  const float* W    = (arm ? WR : WL) + (long)(nb * 11 + 9) * DD * DD;
  const float* bias = (arm ? bR : bL) + (long)(nb * 11 + 9) * DD;
  gemm64_core<0, true>(A, 6, 0, W, bias, nullptr, nullptr,
                       x + (long)arm * BLK, y + (long)arm * BLK, ntile * 64);
}

__global__ __launch_bounds__(256) void k_ffn_g(
    const float* __restrict__ y,
    const float* __restrict__ WL, const float* __restrict__ WR,
    const float* __restrict__ bL, const float* __restrict__ bR,
    const float* __restrict__ lngL, const float* __restrict__ lnbL,
    const float* __restrict__ lngR, const float* __restrict__ lnbR,
    float* __restrict__ x, int nb)
{
  const int bx = blockIdx.x;
  const int arm = bx >> 3, ntile = bx & 7;
  const float* A    = y + (long)arm * BLK;
  const float* W    = (arm ? WR : WL) + (long)(nb * 11 + 10) * DD * DD;
  const float* bias = (arm ? bR : bL) + (long)(nb * 11 + 10) * DD;
  const float* g    = (arm ? lngR : lngL) + (long)nb * DD;
  const float* bb   = (arm ? lnbR : lnbL) + (long)nb * DD;
  gemm64_core<2, false>(A, 6, 0, W, bias, g, bb, nullptr,
                        x + (long)arm * BLK, ntile * 64);
}

__global__ __launch_bounds__(512) void k_attn(
    const float* __restrict__ qkv, const float* __restrict__ kvt,
    const float* __restrict__ kva, const float* __restrict__ gating,
    const float* __restrict__ ropeC, const float* __restrict__ ropeS,
    float* __restrict__ attnout, int nb)
{
  __shared__ float kb[88 * 65];
  __shared__ float vb[88 * 65];
  __shared__ float qb[8 * 65];
  __shared__ float pb[8 * 89];

  const int bx = blockIdx.x;
  const int h = bx & 7, b = (bx >> 3) & 7, arm = bx >> 6;
  const int tid = threadIdx.x;
  const float g = tanhf(gating[nb]);

  {
    const int p = tid >> 6, d = tid & 63;
    const float* qrow = qkv + ((long)(arm * 5 + 0) * 64 + b * 8 + p) * DD + h * 64;
    float v = qrow[d], vp = qrow[d ^ 1];
    float c = ropeC[p * 64 + d], s = ropeS[p * 64 + d];
    qb[p * 65 + d] = v * c + ((d & 1) ? vp : -vp) * s;
  }
  for (int idx = tid; idx < 88 * 64; idx += 512) {
    const int j = idx >> 6, d = idx & 63;
    float kvval, vvval;
    if (j < 8) {
      const float* krow = qkv + ((long)(arm * 5 + 1) * 64 + b * 8 + j) * DD + h * 64;
      float v = krow[d], vp = krow[d ^ 1];
      float c = ropeC[j * 64 + d], s = ropeS[j * 64 + d];
      kvval = v * c + ((d & 1) ? vp : -vp) * s;
      vvval = qkv[((long)(arm * 5 + 2) * 64 + b * 8 + j) * DD + h * 64 + d];
    } else if (j < 16) {
      const int t = j - 8;
      kvval = kva[((long)(nb * 4 + arm * 2 + 0) * 64 + b * 8 + t) * DD + h * 64 + d];
      vvval = kva[((long)(nb * 4 + arm * 2 + 1) * 64 + b * 8 + t) * DD + h * 64 + d];
    } else if (j < 80) {
      const int t = j - 16;
      kvval = g * kvt[((long)(nb * 4 + arm * 2 + 0) * 512 + b * 64 + t) * DD + h * 64 + d];
      vvval = kvt[((long)(nb * 4 + arm * 2 + 1) * 512 + b * 64 + t) * DD + h * 64 + d];
    } else {
      const int t = j - 80;
      const float* krow = qkv + ((long)(arm * 5 + 3) * 64 + b * 8 + t) * DD + h * 64;
      float v = krow[d], vp = krow[d ^ 1];
      float c = ropeC[t * 64 + d], s = ropeS[t * 64 + d];
      kvval = v * c + ((d & 1) ? vp : -vp) * s;
      vvval = qkv[((long)(arm * 5 + 4) * 64 + b * 8 + t) * DD + h * 64 + d];
    }
    kb[j * 65 + d] = kvval;
    vb[j * 65 + d] = vvval;
  }
  __syncthreads();

  const int p = tid >> 6, lane = tid & 63;
  float s0 = 0.f, s1 = 0.f;
  const int j2 = 64 + ((lane < 24) ? lane : 0);
  #pragma unroll 8
  for (int d = 0; d < 64; ++d) {
    const float q = qb[p * 65 + d];
    s0 += q * kb[lane * 65 + d];
    s1 += q * kb[j2 * 65 + d];
  }
  s0 *= 0.125f; s1 *= 0.125f;
  float m = (lane < 24) ? fmaxf(s0, s1) : s0;
  #pragma unroll
  for (int off = 1; off < 64; off <<= 1) m = fmaxf(m, __shfl_xor(m, off));
  const float e0 = __expf(s0 - m);
  const float e1 = (lane < 24) ? __expf(s1 - m) : 0.f;
  float sum = e0 + e1;
  #pragma unroll
  for (int off = 1; off < 64; off <<= 1) sum += __shfl_xor(sum, off);
  const float inv = 1.f / sum;
  pb[p * 89 + lane] = e0 * inv;
  if (lane < 24) pb[p * 89 + 64 + lane] = e1 * inv;
  __syncthreads();

  float acc = 0.f;
  #pragma unroll 8
  for (int j = 0; j < 88; ++j) acc += pb[p * 89 + j] * vb[j * 65 + lane];
  attnout[((long)arm * 64 + b * 8 + p) * DD + h * 64 + lane] = acc;
}

__global__ __launch_bounds__(64) void k_final(
    const float* __restrict__ xp,
    const float* __restrict__ fgL, const float* __restrict__ fbL,
    const float* __restrict__ fgR, const float* __restrict__ fbR,
    const float* __restrict__ fwL, const float* __restrict__ fcbL,
    const float* __restrict__ fwR, const float* __restrict__ fcbR,
    float* __restrict__ out)
{
  const int bx = blockIdx.x;
  const int b = bx & 7, arm = bx >> 3;
  const int tid = threadIdx.x;
  const int p = tid >> 3, k8 = tid & 7;
  const float* xr1 = xp + ((long)arm * 64 + b * 8 + p) * DD;
  const float* xr2 = xr1 + 2 * BLK;

  float s = 0.f, ss = 0.f;
  for (int k = k8 * 64; k < k8 * 64 + 64; k += 4) {
    float4 v = *reinterpret_cast<const float4*>(xr1 + k);
    float4 u = *reinterpret_cast<const float4*>(xr2 + k);
    float a0 = fmaxf(v.x + u.x, 0.f), a1 = fmaxf(v.y + u.y, 0.f);
    float a2 = fmaxf(v.z + u.z, 0.f), a3 = fmaxf(v.w + u.w, 0.f);
    s  += a0 + a1 + a2 + a3;
    ss += a0 * a0 + a1 * a1 + a2 * a2 + a3 * a3;
  }
  s += __shfl_xor(s, 1); ss += __shfl_xor(ss, 1);
  s += __shfl_xor(s, 2); ss += __shfl_xor(ss, 2);
  s += __shfl_xor(s, 4); ss += __shfl_xor(ss, 4);
  const float mu = s * (1.f / 512.f);
  const float var = ss * (1.f / 512.f) - mu * mu;
  const float rstd = rsqrtf(var + 1e-5f);

  const float* g   = arm ? fgR : fgL;
  const float* bb  = arm ? fbR : fbL;
  const float* fw  = arm ? fwR : fwL;
  const float* fcb = arm ? fcbR : fcbL;
  const int j = k8;
  if (j < 7) {
    float acc = 0.f;
    for (int k = 0; k < 512; ++k) {
      const float xv = fmaxf(xr1[k] + xr2[k], 0.f);
      const float xn = (xv - mu) * rstd * g[k] + bb[k];
      acc += xn * fw[k * 7 + j];
    }
    out[((long)(b * 8) + p) * 14 + arm * 7 + j] = acc + fcb[j];
  }
}

// Init: zero xp partials, RoPE tables, barrier counter
__global__ void k_init(float* __restrict__ xp, float* __restrict__ ropeC,
                       float* __restrict__ ropeS, unsigned int* __restrict__ cnt)
{
  const int t = blockIdx.x * 256 + threadIdx.x;
  if (t == 0) *cnt = 0u;
  if (t < 4 * BLK) xp[t] = 0.f;
  if (t < 512) {
    const int p = t >> 6, d = t & 63;
    const float inv = expf(-(float)(d & 31) * (9.210340371976184f / 32.f));
    const float ang = (float)p * inv;
    ropeC[t] = cosf(ang);
    ropeS[t] = sinf(ang);
  }
}

extern "C" void kernel_launch(void* const* d_in, const int* in_sizes, int n_in,
                              void* d_out, int out_size, void* d_ws, size_t ws_size,
                              hipStream_t stream)
{
  (void)in_sizes; (void)n_in; (void)out_size;

  const float* ahs  = (const float*)d_in[0];
  const float* WL   = (const float*)d_in[1];
  const float* bL   = (const float*)d_in[2];
  const float* lngL = (const float*)d_in[3];
  const float* lnbL = (const float*)d_in[4];
  const float* WR   = (const float*)d_in[5];
  const float* bR   = (const float*)d_in[6];
  const float* lngR = (const float*)d_in[7];
  const float* lnbR = (const float*)d_in[8];
  const float* gating = (const float*)d_in[9];
  const float* fgL  = (const float*)d_in[10];
  const float* fbL  = (const float*)d_in[11];
  const float* fgR  = (const float*)d_in[12];
  const float* fbR  = (const float*)d_in[13];
  const float* fwL  = (const float*)d_in[14];
  const float* fcbL = (const float*)d_in[15];
  const float* fwR  = (const float*)d_in[16];
  const float* fcbR = (const float*)d_in[17];
  float* out = (float*)d_out;

  char* ws = (char*)d_ws;
  size_t off = 0;
  unsigned int* cnt = (unsigned int*)(ws + off); off += 256;
  float* ropeC = (float*)(ws + off); off += 512 * 4;
  float* ropeS = (float*)(ws + off); off += 512 * 4;
  float* xp    = (float*)(ws + off); off += (size_t)4 * BLK * 4;   // [kh][arm]
  float* qkvb  = (float*)(ws + off); off += (size_t)10 * BLK * 4;
  float* attno = (float*)(ws + off); off += (size_t)2 * BLK * 4;
  float* yp    = (float*)(ws + off); off += (size_t)4 * BLK * 4;   // [kh][arm]
  float* kvt   = (float*)(ws + off); off += (size_t)NBLK * 4 * 512 * DD * 4;
  float* kva   = (float*)(ws + off); off += (size_t)NBLK * 4 * 64 * DD * 4;
  unsigned short* Wt = (unsigned short*)(ws + off);
  const size_t need = off + (size_t)NBLK * 2 * 7 * WT_SLOT * 2;

  const bool useT = (ws_size >= need);

  k_init<<<dim3(512), dim3(256), 0, stream>>>(xp, ropeC, ropeS, cnt);
  if (useT)
    k_wt<<<dim3(336 * 32), dim3(256), 0, stream>>>(WL, WR, Wt);
  k_p1t <<<dim3(1536), dim3(256), 0, stream>>>(ahs, WL, WR, bL, bR, kvt);
  k_p1a <<<dim3(768),  dim3(256), 0, stream>>>(ahs, WL, WR, bL, bR, kva);

  if (useT) {
    k_fused<<<dim3(NWG), dim3(512), 0, stream>>>(
        xp, qkvb, attno, yp, kvt, kva, Wt, bL, bR,
        lngL, lnbL, lngR, lnbR, gating, ropeC, ropeS,
        fgL, fbL, fgR, fbR, fwL, fcbL, fwR, fcbR, out, cnt);
  } else {
    for (int nb = 0; nb < NBLK; ++nb) {
      k_qkv_g<<<dim3(80),  dim3(256), 0, stream>>>(xp, WL, WR, bL, bR, qkvb, nb);
      k_attn<<<dim3(128), dim3(512), 0, stream>>>(qkvb, kvt, kva, gating, ropeC, ropeS, attno, nb);
      k_proj_g<<<dim3(16),  dim3(256), 0, stream>>>(attno, WL, WR, bL, bR, xp, yp, nb);
      k_ffn_g<<<dim3(16),  dim3(256), 0, stream>>>(yp, WL, WR, bL, bR, lngL, lnbL, lngR, lnbR, xp, nb);
    }
    k_final<<<dim3(16), dim3(64), 0, stream>>>(xp, fgL, fbL, fgR, fbR, fwL, fcbL, fwR, fcbR, out);
  }
}

// Round 5
// 3080.888 us; speedup vs baseline: 2.4190x; 2.4190x over previous
//
#include <hip/hip_runtime.h>

#define DD 512
#define NBLK 24
#define BLK (64 * DD)            // one 64-row arm block (floats)
#define WT_SLOT 524288           // shorts per transposed matrix (512*512*2)
#define FNWG 160                 // fused-kernel grid (= qkv phase width)

typedef short s16x8 __attribute__((ext_vector_type(8)));
typedef float f32x4 __attribute__((ext_vector_type(4)));

union FragU { s16x8 s; __bf16 h[8]; };

__device__ __forceinline__ f32x4 mfma16(s16x8 a, s16x8 b, f32x4 c) {
  return __builtin_amdgcn_mfma_f32_16x16x32_bf16(a, b, c, 0, 0, 0);
}

__device__ __forceinline__ void bsplit(float v, __bf16& hi, __bf16& lo) {
  hi = (__bf16)v;
  lo = (__bf16)(v - (float)hi);
}

// Device-scope barrier, cache-friendly protocol:
//   arrive: RELEASE fetch_add (one wbl2 per wg — makes our stores visible)
//   spin:   RELAXED loads (no cache invalidates) + s_sleep
//   depart: ONE ACQUIRE load (one buffer_inv per wg — pulls others' stores)
// The round-4 version polled with ACQUIRE => per-poll L2 invalidate storm
// across all XCDs => 82 GB/s effective HBM. Do not reintroduce.
__device__ __forceinline__ void gbar(unsigned int* cnt, unsigned int target) {
  __syncthreads();
  if (threadIdx.x == 0) {
    __hip_atomic_fetch_add(cnt, 1u, __ATOMIC_RELEASE, __HIP_MEMORY_SCOPE_AGENT);
    while (__hip_atomic_load(cnt, __ATOMIC_RELAXED, __HIP_MEMORY_SCOPE_AGENT) < target)
      __builtin_amdgcn_s_sleep(16);
    (void)__hip_atomic_load(cnt, __ATOMIC_ACQUIRE, __HIP_MEMORY_SCOPE_AGENT);
  }
  __syncthreads();
}

__constant__ int c_wmap[7] = {0, 1, 2, 7, 8, 9, 10};

// ---------------------------------------------------------------------------
// Gather GEMM core (k_pre's p1a range + ws-too-small fallback path)
// ---------------------------------------------------------------------------
template<int AMODE, bool RESID>
__device__ __forceinline__ void gemm64_core(
    const float* __restrict__ Abase, int rshift, long sOuter,
    const float* __restrict__ Wf,
    const float* __restrict__ bias,
    const float* __restrict__ lng, const float* __restrict__ lnb,
    const float* __restrict__ resid,
    float* __restrict__ outF,
    int n0)
{
  const int tid  = threadIdx.x;
  const int wave = tid >> 6;
  const int lane = tid & 63;
  const int l15  = lane & 15;
  const int lq   = lane >> 4;

  const int rowA = wave * 16 + l15;
  const float* Arow = Abase + (long)(rowA >> rshift) * sOuter
                            + (long)(rowA & ((1 << rshift) - 1)) * DD;

  float mu = 0.f, rstd = 0.f;
  if constexpr (AMODE == 2) {
    float s = 0.f, ss = 0.f;
    const float* p = Arow + lq * 128;
    #pragma unroll
    for (int k = 0; k < 128; k += 4) {
      float4 v = *reinterpret_cast<const float4*>(p + k);
      s  += v.x + v.y + v.z + v.w;
      ss += v.x * v.x + v.y * v.y + v.z * v.z + v.w * v.w;
    }
    s += __shfl_xor(s, 16); ss += __shfl_xor(ss, 16);
    s += __shfl_xor(s, 32); ss += __shfl_xor(ss, 32);
    mu = s * (1.f / 512.f);
    float var = ss * (1.f / 512.f) - mu * mu;
    rstd = rsqrtf(var + 1e-5f);
  }

  f32x4 acc[4] = {};

  for (int ks = 0; ks < 16; ++ks) {
    const int k0 = ks * 32 + lq * 8;
    FragU ahi, alo;
    {
      float4 v0 = *reinterpret_cast<const float4*>(Arow + k0);
      float4 v1 = *reinterpret_cast<const float4*>(Arow + k0 + 4);
      float t0[8] = {v0.x, v0.y, v0.z, v0.w, v1.x, v1.y, v1.z, v1.w};
      if constexpr (AMODE == 2) {
        float4 g0 = *reinterpret_cast<const float4*>(lng + k0);
        float4 g1 = *reinterpret_cast<const float4*>(lng + k0 + 4);
        float4 c0 = *reinterpret_cast<const float4*>(lnb + k0);
        float4 c1 = *reinterpret_cast<const float4*>(lnb + k0 + 4);
        float gg[8] = {g0.x, g0.y, g0.z, g0.w, g1.x, g1.y, g1.z, g1.w};
        float cc[8] = {c0.x, c0.y, c0.z, c0.w, c1.x, c1.y, c1.z, c1.w};
        #pragma unroll
        for (int e = 0; e < 8; ++e) {
          float v = (t0[e] - mu) * rstd * gg[e] + cc[e];
          bsplit(v, ahi.h[e], alo.h[e]);
        }
      } else {
        #pragma unroll
        for (int e = 0; e < 8; ++e) {
          float v = t0[e];
          if constexpr (AMODE == 1) v = fmaxf(v, 0.f);
          bsplit(v, ahi.h[e], alo.h[e]);
        }
      }
    }
    const float* wp = Wf + (long)k0 * DD + n0 + l15;
    #pragma unroll
    for (int j = 0; j < 4; ++j) {
      FragU bhi, blo;
      #pragma unroll
      for (int e = 0; e < 8; ++e) {
        float w = wp[(long)e * DD + j * 16];
        bsplit(w, bhi.h[e], blo.h[e]);
      }
      acc[j] = mfma16(ahi.s, bhi.s, acc[j]);
      acc[j] = mfma16(ahi.s, blo.s, acc[j]);
      acc[j] = mfma16(alo.s, bhi.s, acc[j]);
    }
  }

  const int mbase = wave * 16 + lq * 4;
  #pragma unroll
  for (int j = 0; j < 4; ++j) {
    const int n = n0 + j * 16 + l15;
    const float bv = bias[n];
    #pragma unroll
    for (int r = 0; r < 4; ++r) {
      const int m = mbase + r;
      float v = acc[j][r] + bv;
      if constexpr (RESID) v += fmaxf(resid[(long)m * DD + n], 0.f);
      outF[(long)m * DD + n] = v;
    }
  }
}

// ---------------------------------------------------------------------------
// Transposed-weight core, 512 threads (8 waves): 64 rows x 32 cols tile.
// ---------------------------------------------------------------------------
template<int AMODE, bool A2P>
__device__ __forceinline__ void gemmT512(
    const float* __restrict__ A1, const float* __restrict__ A2,
    const unsigned short* __restrict__ Wt,   // slot base
    const float* __restrict__ bias, int addBias,
    const float* __restrict__ lng, const float* __restrict__ lnb,
    const float* __restrict__ r1, const float* __restrict__ r2,
    float* __restrict__ outF, int n0, int ks0, int ks1)
{
  const int tid  = threadIdx.x;
  const int wave = tid >> 6;
  const int mq   = wave & 3;
  const int nh   = wave >> 2;
  const int lane = tid & 63;
  const int l15  = lane & 15;
  const int lq   = lane >> 4;

  const int rowA = mq * 16 + l15;
  const float* A1row = A1 + (long)rowA * DD;
  const float* A2row = A2P ? (A2 + (long)rowA * DD) : nullptr;

  float mu = 0.f, rstd = 0.f;
  if constexpr (AMODE == 2) {
    float s = 0.f, ss = 0.f;
    const float* p1 = A1row + lq * 128;
    const float* p2 = A2P ? (A2row + lq * 128) : nullptr;
    #pragma unroll
    for (int k = 0; k < 128; k += 4) {
      float4 v = *reinterpret_cast<const float4*>(p1 + k);
      float vx = v.x, vy = v.y, vz = v.z, vw = v.w;
      if constexpr (A2P) {
        float4 u = *reinterpret_cast<const float4*>(p2 + k);
        vx += u.x; vy += u.y; vz += u.z; vw += u.w;
      }
      s  += vx + vy + vz + vw;
      ss += vx * vx + vy * vy + vz * vz + vw * vw;
    }
    s += __shfl_xor(s, 16); ss += __shfl_xor(ss, 16);
    s += __shfl_xor(s, 32); ss += __shfl_xor(ss, 32);
    mu = s * (1.f / 512.f);
    float var = ss * (1.f / 512.f) - mu * mu;
    rstd = rsqrtf(var + 1e-5f);
  }

  f32x4 acc = {};
  const long ngBase = (long)((n0 + nh * 16) >> 4) * 64;

  for (int ks = ks0; ks < ks1; ++ks) {
    const int k0 = ks * 32 + lq * 8;
    FragU ahi, alo;
    {
      float4 v0 = *reinterpret_cast<const float4*>(A1row + k0);
      float4 v1 = *reinterpret_cast<const float4*>(A1row + k0 + 4);
      float t0[8] = {v0.x, v0.y, v0.z, v0.w, v1.x, v1.y, v1.z, v1.w};
      if constexpr (A2P) {
        float4 u0 = *reinterpret_cast<const float4*>(A2row + k0);
        float4 u1 = *reinterpret_cast<const float4*>(A2row + k0 + 4);
        t0[0] += u0.x; t0[1] += u0.y; t0[2] += u0.z; t0[3] += u0.w;
        t0[4] += u1.x; t0[5] += u1.y; t0[6] += u1.z; t0[7] += u1.w;
      }
      if constexpr (AMODE == 2) {
        float4 g0 = *reinterpret_cast<const float4*>(lng + k0);
        float4 g1 = *reinterpret_cast<const float4*>(lng + k0 + 4);
        float4 c0 = *reinterpret_cast<const float4*>(lnb + k0);
        float4 c1 = *reinterpret_cast<const float4*>(lnb + k0 + 4);
        float gg[8] = {g0.x, g0.y, g0.z, g0.w, g1.x, g1.y, g1.z, g1.w};
        float cc[8] = {c0.x, c0.y, c0.z, c0.w, c1.x, c1.y, c1.z, c1.w};
        #pragma unroll
        for (int e = 0; e < 8; ++e) {
          float v = (t0[e] - mu) * rstd * gg[e] + cc[e];
          bsplit(v, ahi.h[e], alo.h[e]);
        }
      } else {
        #pragma unroll
        for (int e = 0; e < 8; ++e) {
          float v = t0[e];
          if constexpr (AMODE == 1) v = fmaxf(v, 0.f);
          bsplit(v, ahi.h[e], alo.h[e]);
        }
      }
    }
    const unsigned short* wp = Wt + ((ngBase + (ks * 4 + lq)) * 16 + l15) * 16;
    s16x8 bhi = *reinterpret_cast<const s16x8*>(wp);
    s16x8 blo = *reinterpret_cast<const s16x8*>(wp + 8);
    acc = mfma16(ahi.s, bhi, acc);
    acc = mfma16(ahi.s, blo, acc);
    acc = mfma16(alo.s, bhi, acc);
  }

  const int mbase = mq * 16 + lq * 4;
  const int n = n0 + nh * 16 + l15;
  const float bv = addBias ? bias[n] : 0.f;
  #pragma unroll
  for (int r = 0; r < 4; ++r) {
    const int m = mbase + r;
    float v = acc[r] + bv;
    if (r1) {
      float rv = r1[(long)m * DD + n];
      if (r2) rv += r2[(long)m * DD + n];
      v += fmaxf(rv, 0.f);
    }
    outF[(long)m * DD + n] = v;
  }
}

#define LDSW 40

// ---------------------------------------------------------------------------
// k_pre: merged phase-0/1. wg ranges:
//   [0, 1536)                : kt/vt LDS-tiled GEMM (p1t)
//   [1536, 1536+wtC)         : weight transpose (wt; wtC = 10752 or 0)
//   [1536+wtC, 2304+wtC)     : ka/va gather GEMM (p1a)
// All ranges independent (disjoint outputs), no sync needed.
// ---------------------------------------------------------------------------
__global__ __launch_bounds__(256) void k_pre(
    const float* __restrict__ ahs,
    const float* __restrict__ WL, const float* __restrict__ WR,
    const float* __restrict__ bL, const float* __restrict__ bR,
    float* __restrict__ kvt, float* __restrict__ kva,
    unsigned short* __restrict__ Wt, int wtC)
{
  const int bx = blockIdx.x;

  if (bx < 1536) {
    // ---------------- p1t: kt/vt ----------------
    __shared__ __align__(16) unsigned short Ab[2][64 * LDSW];
    __shared__ __align__(16) unsigned short Wb[4][2][64 * LDSW];

    const int ntile = bx & 7, mtile = (bx >> 3) & 7, nb = bx >> 6;
    const int n0 = ntile * 64;

    const float* Abase = ahs + (long)(mtile * 25 + nb + 1) * 80 * DD;
    const float* Wp[4];
    const float* bp[4];
    #pragma unroll
    for (int o = 0; o < 4; ++o) {
      const int arm = o >> 1, kv = o & 1;
      Wp[o] = (arm ? WR : WL) + (long)(nb * 11 + 3 + kv) * DD * DD;
      bp[o] = (arm ? bR : bL) + (long)(nb * 11 + 3 + kv) * DD;
    }

    const int tid  = threadIdx.x;
    const int srow = tid >> 2;
    const int skq  = (tid & 3) * 8;
    const int wave = tid >> 6, lane = tid & 63, l15 = lane & 15, lq = lane >> 4;

    f32x4 acc[4][4] = {};
    float aR[8];
    float wRg[4][8];

    auto loadStage = [&](int kbase) {
      const float* ap = Abase + (long)srow * DD + kbase + skq;
      float4 v0 = *reinterpret_cast<const float4*>(ap);
      float4 v1 = *reinterpret_cast<const float4*>(ap + 4);
      aR[0] = v0.x; aR[1] = v0.y; aR[2] = v0.z; aR[3] = v0.w;
      aR[4] = v1.x; aR[5] = v1.y; aR[6] = v1.z; aR[7] = v1.w;
      #pragma unroll
      for (int o = 0; o < 4; ++o) {
        #pragma unroll
        for (int e = 0; e < 8; ++e)
          wRg[o][e] = Wp[o][(long)(kbase + skq + e) * DD + n0 + srow];
      }
    };

    loadStage(0);
    for (int s = 0; s < 16; ++s) {
      __syncthreads();
      {
        FragU uh, ul;
        #pragma unroll
        for (int e = 0; e < 8; ++e) bsplit(aR[e], uh.h[e], ul.h[e]);
        *reinterpret_cast<s16x8*>(&Ab[0][srow * LDSW + skq]) = uh.s;
        *reinterpret_cast<s16x8*>(&Ab[1][srow * LDSW + skq]) = ul.s;
        #pragma unroll
        for (int o = 0; o < 4; ++o) {
          FragU wh, wl;
          #pragma unroll
          for (int e = 0; e < 8; ++e) bsplit(wRg[o][e], wh.h[e], wl.h[e]);
          *reinterpret_cast<s16x8*>(&Wb[o][0][srow * LDSW + skq]) = wh.s;
          *reinterpret_cast<s16x8*>(&Wb[o][1][srow * LDSW + skq]) = wl.s;
        }
      }
      __syncthreads();
      if (s < 15) loadStage((s + 1) * 32);
      s16x8 ahi = *reinterpret_cast<const s16x8*>(&Ab[0][(wave * 16 + l15) * LDSW + lq * 8]);
      s16x8 alo = *reinterpret_cast<const s16x8*>(&Ab[1][(wave * 16 + l15) * LDSW + lq * 8]);
      #pragma unroll
      for (int o = 0; o < 4; ++o) {
        #pragma unroll
        for (int j = 0; j < 4; ++j) {
          s16x8 bhi = *reinterpret_cast<const s16x8*>(&Wb[o][0][(j * 16 + l15) * LDSW + lq * 8]);
          s16x8 blo = *reinterpret_cast<const s16x8*>(&Wb[o][1][(j * 16 + l15) * LDSW + lq * 8]);
          acc[o][j] = mfma16(ahi, bhi, acc[o][j]);
          acc[o][j] = mfma16(ahi, blo, acc[o][j]);
          acc[o][j] = mfma16(alo, bhi, acc[o][j]);
        }
      }
    }

    const int mbase = mtile * 64 + wave * 16 + lq * 4;
    #pragma unroll
    for (int o = 0; o < 4; ++o) {
      float* outb = kvt + (long)(nb * 4 + o) * 512 * DD;
      #pragma unroll
      for (int j = 0; j < 4; ++j) {
        const int n = n0 + j * 16 + l15;
        const float bv = bp[o][n];
        #pragma unroll
        for (int r = 0; r < 4; ++r)
          outb[(long)(mbase + r) * DD + n] = acc[o][j][r] + bv;
      }
    }
  } else if (bx < 1536 + wtC) {
    // ---------------- wt: weight transpose ----------------
    const int wbx = bx - 1536;
    const int ng = wbx & 31, slot = wbx >> 5;
    const int wi7 = slot % 7, nb2 = slot / 7;
    const int arm = nb2 & 1, nb = nb2 >> 1;
    const float* Wsrc = (arm ? WR : WL) + (long)(nb * 11 + c_wmap[wi7]) * DD * DD;

    const int t = threadIdx.x;
    const int k8 = t >> 2, lbase = (t & 3) * 4;

    unsigned short hi[4][8], lo[4][8];
    #pragma unroll
    for (int e = 0; e < 8; ++e) {
      float4 v = *reinterpret_cast<const float4*>(
          Wsrc + (long)(k8 * 8 + e) * DD + ng * 16 + lbase);
      float vv[4] = {v.x, v.y, v.z, v.w};
      #pragma unroll
      for (int c = 0; c < 4; ++c) {
        __bf16 h, l;
        bsplit(vv[c], h, l);
        union { __bf16 b; unsigned short u; } ch, cl; ch.b = h; cl.b = l;
        hi[c][e] = ch.u; lo[c][e] = cl.u;
      }
    }
    unsigned short* dst = Wt + (long)slot * WT_SLOT
                        + ((long)(ng * 64 + k8) * 16 + lbase) * 16;
    #pragma unroll
    for (int c = 0; c < 4; ++c) {
      s16x8 a, b;
      #pragma unroll
      for (int e = 0; e < 8; ++e) { ((short*)&a)[e] = hi[c][e]; ((short*)&b)[e] = lo[c][e]; }
      *reinterpret_cast<s16x8*>(dst + c * 16)     = a;
      *reinterpret_cast<s16x8*>(dst + c * 16 + 8) = b;
    }
  } else {
    // ---------------- p1a: ka/va ----------------
    const int pbx = bx - 1536 - wtC;
    const int ntile = pbx & 7, kv = (pbx >> 3) & 1, arm = (pbx >> 4) & 1, nb = pbx >> 5;
    const float* Abase = ahs + ((long)(nb + 1) * 80 + 64 + arm * 8) * DD;
    const float* W    = (arm ? WR : WL) + (long)(nb * 11 + 5 + kv) * DD * DD;
    const float* bias = (arm ? bR : bL) + (long)(nb * 11 + 5 + kv) * DD;
    float* out = kva + (long)(nb * 4 + arm * 2 + kv) * 64 * DD;
    gemm64_core<0, false>(Abase, 3, (long)25 * 80 * DD, W, bias,
                          nullptr, nullptr, nullptr, out, ntile * 64);
  }
}

// ---------------------------------------------------------------------------
// FUSED sequential scan: all 24 blocks + final head in ONE kernel.
// 160 wgs x 512 threads; fixed software global barrier between phases.
// ---------------------------------------------------------------------------
__global__ __launch_bounds__(512, 4) void k_fused(
    float* __restrict__ xp, float* __restrict__ qkvb,
    float* __restrict__ attno, float* __restrict__ yp,
    const float* __restrict__ kvt, const float* __restrict__ kva,
    const unsigned short* __restrict__ Wt,
    const float* __restrict__ bL, const float* __restrict__ bR,
    const float* __restrict__ lngL, const float* __restrict__ lnbL,
    const float* __restrict__ lngR, const float* __restrict__ lnbR,
    const float* __restrict__ gating,
    const float* __restrict__ ropeC, const float* __restrict__ ropeS,
    const float* __restrict__ fgL, const float* __restrict__ fbL,
    const float* __restrict__ fgR, const float* __restrict__ fbR,
    const float* __restrict__ fwL, const float* __restrict__ fcbL,
    const float* __restrict__ fwR, const float* __restrict__ fcbR,
    float* __restrict__ out, unsigned int* __restrict__ cnt)
{
  __shared__ float kb[88 * 65];
  __shared__ float vb[88 * 65];
  __shared__ float qb[8 * 65];
  __shared__ float pb[8 * 89];

  const int wg  = blockIdx.x;
  const int tid = threadIdx.x;
  unsigned int bi = 0;

  for (int nb = 0; nb < NBLK; ++nb) {
    // ---------------- QKV: 160 tiles of 64x32 ----------------
    {
      const int arm = wg / 80;
      const int rem = wg - arm * 80;
      const int wi = rem >> 4, nt = rem & 15;
      const int sel = (wi < 3) ? arm : (1 - arm);
      gemmT512<1, true>(
          xp + (long)sel * BLK, xp + (long)(2 + sel) * BLK,
          Wt + (((long)nb * 2 + arm) * 7 + wi) * WT_SLOT,
          (arm ? bR : bL) + ((long)nb * 11 + c_wmap[wi]) * DD, 1,
          nullptr, nullptr, nullptr, nullptr,
          qkvb + ((long)arm * 5 + wi) * BLK, nt * 32, 0, 16);
    }
    gbar(cnt, ++bi * FNWG);

    // ---------------- ATTN: 128 wgs (arm,b,h) ----------------
    if (wg < 128) {
      const int h = wg & 7, b = (wg >> 3) & 7, arm = wg >> 6;
      const float g = tanhf(gating[nb]);

      {
        const int p = tid >> 6, d = tid & 63;
        const float* qrow = qkvb + ((long)(arm * 5 + 0) * 64 + b * 8 + p) * DD + h * 64;
        float v = qrow[d], vp = qrow[d ^ 1];
        float c = ropeC[p * 64 + d], s = ropeS[p * 64 + d];
        qb[p * 65 + d] = v * c + ((d & 1) ? vp : -vp) * s;
      }
      for (int idx = tid; idx < 88 * 64; idx += 512) {
        const int j = idx >> 6, d = idx & 63;
        float kvval, vvval;
        if (j < 8) {
          const float* krow = qkvb + ((long)(arm * 5 + 1) * 64 + b * 8 + j) * DD + h * 64;
          float v = krow[d], vp = krow[d ^ 1];
          float c = ropeC[j * 64 + d], s = ropeS[j * 64 + d];
          kvval = v * c + ((d & 1) ? vp : -vp) * s;
          vvval = qkvb[((long)(arm * 5 + 2) * 64 + b * 8 + j) * DD + h * 64 + d];
        } else if (j < 16) {
          const int t = j - 8;
          kvval = kva[((long)(nb * 4 + arm * 2 + 0) * 64 + b * 8 + t) * DD + h * 64 + d];
          vvval = kva[((long)(nb * 4 + arm * 2 + 1) * 64 + b * 8 + t) * DD + h * 64 + d];
        } else if (j < 80) {
          const int t = j - 16;
          kvval = g * kvt[((long)(nb * 4 + arm * 2 + 0) * 512 + b * 64 + t) * DD + h * 64 + d];
          vvval = kvt[((long)(nb * 4 + arm * 2 + 1) * 512 + b * 64 + t) * DD + h * 64 + d];
        } else {
          const int t = j - 80;
          const float* krow = qkvb + ((long)(arm * 5 + 3) * 64 + b * 8 + t) * DD + h * 64;
          float v = krow[d], vp = krow[d ^ 1];
          float c = ropeC[t * 64 + d], s = ropeS[t * 64 + d];
          kvval = v * c + ((d & 1) ? vp : -vp) * s;
          vvval = qkvb[((long)(arm * 5 + 4) * 64 + b * 8 + t) * DD + h * 64 + d];
        }
        kb[j * 65 + d] = kvval;
        vb[j * 65 + d] = vvval;
      }
      __syncthreads();

      const int p = tid >> 6, lane = tid & 63;
      float s0 = 0.f, s1 = 0.f;
      const int j2 = 64 + ((lane < 24) ? lane : 0);
      #pragma unroll 8
      for (int d = 0; d < 64; ++d) {
        const float q = qb[p * 65 + d];
        s0 += q * kb[lane * 65 + d];
        s1 += q * kb[j2 * 65 + d];
      }
      s0 *= 0.125f; s1 *= 0.125f;
      float m = (lane < 24) ? fmaxf(s0, s1) : s0;
      #pragma unroll
      for (int off = 1; off < 64; off <<= 1) m = fmaxf(m, __shfl_xor(m, off));
      const float e0 = __expf(s0 - m);
      const float e1 = (lane < 24) ? __expf(s1 - m) : 0.f;
      float sum = e0 + e1;
      #pragma unroll
      for (int off = 1; off < 64; off <<= 1) sum += __shfl_xor(sum, off);
      const float inv = 1.f / sum;
      pb[p * 89 + lane] = e0 * inv;
      if (lane < 24) pb[p * 89 + 64 + lane] = e1 * inv;
      __syncthreads();

      float acc = 0.f;
      #pragma unroll 8
      for (int j = 0; j < 88; ++j) acc += pb[p * 89 + j] * vb[j * 65 + lane];
      attno[((long)arm * 64 + b * 8 + p) * DD + h * 64 + lane] = acc;
    }
    gbar(cnt, ++bi * FNWG);

    // ---------------- PROJ: 64 wgs (arm,kh,nt), K-split 2 ----------------
    if (wg < 64) {
      const int arm = wg >> 5, kh = (wg >> 4) & 1, nt = wg & 15;
      gemmT512<0, false>(
          attno + (long)arm * BLK, nullptr,
          Wt + (((long)nb * 2 + arm) * 7 + 5) * WT_SLOT,
          (arm ? bR : bL) + ((long)nb * 11 + 9) * DD, kh == 0,
          nullptr, nullptr,
          kh == 0 ? xp + (long)arm * BLK : nullptr,
          kh == 0 ? xp + (long)(2 + arm) * BLK : nullptr,
          yp + (long)(kh * 2 + arm) * BLK, nt * 32, kh * 8, kh * 8 + 8);
    }
    gbar(cnt, ++bi * FNWG);

    // ---------------- FFN: 64 wgs ----------------
    if (wg < 64) {
      const int arm = wg >> 5, kh = (wg >> 4) & 1, nt = wg & 15;
      gemmT512<2, true>(
          yp + (long)arm * BLK, yp + (long)(2 + arm) * BLK,
          Wt + (((long)nb * 2 + arm) * 7 + 6) * WT_SLOT,
          (arm ? bR : bL) + ((long)nb * 11 + 10) * DD, kh == 0,
          (arm ? lngR : lngL) + (long)nb * DD, (arm ? lnbR : lnbL) + (long)nb * DD,
          nullptr, nullptr,
          xp + (long)(kh * 2 + arm) * BLK, nt * 32, kh * 8, kh * 8 + 8);
    }
    gbar(cnt, ++bi * FNWG);
  }

  // ---------------- FINAL head: 16 wgs x 64 threads ----------------
  if (wg < 16 && tid < 64) {
    const int b = wg & 7, arm = wg >> 3;
    const int p = tid >> 3, k8 = tid & 7;
    const float* xr1 = xp + ((long)arm * 64 + b * 8 + p) * DD;
    const float* xr2 = xr1 + 2 * BLK;

    float s = 0.f, ss = 0.f;
    for (int k = k8 * 64; k < k8 * 64 + 64; k += 4) {
      float4 v = *reinterpret_cast<const float4*>(xr1 + k);
      float4 u = *reinterpret_cast<const float4*>(xr2 + k);
      float a0 = fmaxf(v.x + u.x, 0.f), a1 = fmaxf(v.y + u.y, 0.f);
      float a2 = fmaxf(v.z + u.z, 0.f), a3 = fmaxf(v.w + u.w, 0.f);
      s  += a0 + a1 + a2 + a3;
      ss += a0 * a0 + a1 * a1 + a2 * a2 + a3 * a3;
    }
    s += __shfl_xor(s, 1); ss += __shfl_xor(ss, 1);
    s += __shfl_xor(s, 2); ss += __shfl_xor(ss, 2);
    s += __shfl_xor(s, 4); ss += __shfl_xor(ss, 4);
    const float mu = s * (1.f / 512.f);
    const float var = ss * (1.f / 512.f) - mu * mu;
    const float rstd = rsqrtf(var + 1e-5f);

    const float* g   = arm ? fgR : fgL;
    const float* bb  = arm ? fbR : fbL;
    const float* fw  = arm ? fwR : fwL;
    const float* fcb = arm ? fcbR : fcbL;
    const int j = k8;
    if (j < 7) {
      float acc = 0.f;
      for (int k = 0; k < 512; ++k) {
        const float xv = fmaxf(xr1[k] + xr2[k], 0.f);
        const float xn = (xv - mu) * rstd * g[k] + bb[k];
        acc += xn * fw[k * 7 + j];
      }
      out[((long)(b * 8) + p) * 14 + arm * 7 + j] = acc + fcb[j];
    }
  }
}

// ---------------------------------------------------------------------------
// Fallback (gather path) kernels — only used when ws can't hold Wt
// ---------------------------------------------------------------------------
__global__ __launch_bounds__(256) void k_qkv_g(
    const float* __restrict__ x,
    const float* __restrict__ WL, const float* __restrict__ WR,
    const float* __restrict__ bL, const float* __restrict__ bR,
    float* __restrict__ qkv, int nb)
{
  const int bx = blockIdx.x;
  const int arm = bx / 40;
  const int rem = bx - arm * 40;
  const int wi = rem >> 3, ntile = rem & 7;
  const int w = (wi < 3) ? wi : wi + 4;
  const float* A    = x + (long)((wi < 3) ? arm : (1 - arm)) * BLK;
  const float* W    = (arm ? WR : WL) + (long)(nb * 11 + w) * DD * DD;
  const float* bias = (arm ? bR : bL) + (long)(nb * 11 + w) * DD;
  float* out = qkv + (long)(arm * 5 + wi) * BLK;
  gemm64_core<1, false>(A, 6, 0, W, bias, nullptr, nullptr, nullptr,
                        out, ntile * 64);
}

__global__ __launch_bounds__(256) void k_proj_g(
    const float* __restrict__ attno,
    const float* __restrict__ WL, const float* __restrict__ WR,
    const float* __restrict__ bL, const float* __restrict__ bR,
    const float* __restrict__ x, float* __restrict__ y, int nb)
{
  const int bx = blockIdx.x;
  const int arm = bx >> 3, ntile = bx & 7;
  const float* A    = attno + (long)arm * BLK;
  const float* W    = (arm ? WR : WL) + (long)(nb * 11 + 9) * DD * DD;
  const float* bias = (arm ? bR : bL) + (long)(nb * 11 + 9) * DD;
  gemm64_core<0, true>(A, 6, 0, W, bias, nullptr, nullptr,
                       x + (long)arm * BLK, y + (long)arm * BLK, ntile * 64);
}

__global__ __launch_bounds__(256) void k_ffn_g(
    const float* __restrict__ y,
    const float* __restrict__ WL, const float* __restrict__ WR,
    const float* __restrict__ bL, const float* __restrict__ bR,
    const float* __restrict__ lngL, const float* __restrict__ lnbL,
    const float* __restrict__ lngR, const float* __restrict__ lnbR,
    float* __restrict__ x, int nb)
{
  const int bx = blockIdx.x;
  const int arm = bx >> 3, ntile = bx & 7;
  const float* A    = y + (long)arm * BLK;
  const float* W    = (arm ? WR : WL) + (long)(nb * 11 + 10) * DD * DD;
  const float* bias = (arm ? bR : bL) + (long)(nb * 11 + 10) * DD;
  const float* g    = (arm ? lngR : lngL) + (long)nb * DD;
  const float* bb   = (arm ? lnbR : lnbL) + (long)nb * DD;
  gemm64_core<2, false>(A, 6, 0, W, bias, g, bb, nullptr,
                        x + (long)arm * BLK, ntile * 64);
}

__global__ __launch_bounds__(512) void k_attn(
    const float* __restrict__ qkv, const float* __restrict__ kvt,
    const float* __restrict__ kva, const float* __restrict__ gating,
    const float* __restrict__ ropeC, const float* __restrict__ ropeS,
    float* __restrict__ attnout, int nb)
{
  __shared__ float kb[88 * 65];
  __shared__ float vb[88 * 65];
  __shared__ float qb[8 * 65];
  __shared__ float pb[8 * 89];

  const int bx = blockIdx.x;
  const int h = bx & 7, b = (bx >> 3) & 7, arm = bx >> 6;
  const int tid = threadIdx.x;
  const float g = tanhf(gating[nb]);

  {
    const int p = tid >> 6, d = tid & 63;
    const float* qrow = qkv + ((long)(arm * 5 + 0) * 64 + b * 8 + p) * DD + h * 64;
    float v = qrow[d], vp = qrow[d ^ 1];
    float c = ropeC[p * 64 + d], s = ropeS[p * 64 + d];
    qb[p * 65 + d] = v * c + ((d & 1) ? vp : -vp) * s;
  }
  for (int idx = tid; idx < 88 * 64; idx += 512) {
    const int j = idx >> 6, d = idx & 63;
    float kvval, vvval;
    if (j < 8) {
      const float* krow = qkv + ((long)(arm * 5 + 1) * 64 + b * 8 + j) * DD + h * 64;
      float v = krow[d], vp = krow[d ^ 1];
      float c = ropeC[j * 64 + d], s = ropeS[j * 64 + d];
      kvval = v * c + ((d & 1) ? vp : -vp) * s;
      vvval = qkv[((long)(arm * 5 + 2) * 64 + b * 8 + j) * DD + h * 64 + d];
    } else if (j < 16) {
      const int t = j - 8;
      kvval = kva[((long)(nb * 4 + arm * 2 + 0) * 64 + b * 8 + t) * DD + h * 64 + d];
      vvval = kva[((long)(nb * 4 + arm * 2 + 1) * 64 + b * 8 + t) * DD + h * 64 + d];
    } else if (j < 80) {
      const int t = j - 16;
      kvval = g * kvt[((long)(nb * 4 + arm * 2 + 0) * 512 + b * 64 + t) * DD + h * 64 + d];
      vvval = kvt[((long)(nb * 4 + arm * 2 + 1) * 512 + b * 64 + t) * DD + h * 64 + d];
    } else {
      const int t = j - 80;
      const float* krow = qkv + ((long)(arm * 5 + 3) * 64 + b * 8 + t) * DD + h * 64;
      float v = krow[d], vp = krow[d ^ 1];
      float c = ropeC[t * 64 + d], s = ropeS[t * 64 + d];
      kvval = v * c + ((d & 1) ? vp : -vp) * s;
      vvval = qkv[((long)(arm * 5 + 4) * 64 + b * 8 + t) * DD + h * 64 + d];
    }
    kb[j * 65 + d] = kvval;
    vb[j * 65 + d] = vvval;
  }
  __syncthreads();

  const int p = tid >> 6, lane = tid & 63;
  float s0 = 0.f, s1 = 0.f;
  const int j2 = 64 + ((lane < 24) ? lane : 0);
  #pragma unroll 8
  for (int d = 0; d < 64; ++d) {
    const float q = qb[p * 65 + d];
    s0 += q * kb[lane * 65 + d];
    s1 += q * kb[j2 * 65 + d];
  }
  s0 *= 0.125f; s1 *= 0.125f;
  float m = (lane < 24) ? fmaxf(s0, s1) : s0;
  #pragma unroll
  for (int off = 1; off < 64; off <<= 1) m = fmaxf(m, __shfl_xor(m, off));
  const float e0 = __expf(s0 - m);
  const float e1 = (lane < 24) ? __expf(s1 - m) : 0.f;
  float sum = e0 + e1;
  #pragma unroll
  for (int off = 1; off < 64; off <<= 1) sum += __shfl_xor(sum, off);
  const float inv = 1.f / sum;
  pb[p * 89 + lane] = e0 * inv;
  if (lane < 24) pb[p * 89 + 64 + lane] = e1 * inv;
  __syncthreads();

  float acc = 0.f;
  #pragma unroll 8
  for (int j = 0; j < 88; ++j) acc += pb[p * 89 + j] * vb[j * 65 + lane];
  attnout[((long)arm * 64 + b * 8 + p) * DD + h * 64 + lane] = acc;
}

__global__ __launch_bounds__(64) void k_final(
    const float* __restrict__ xp,
    const float* __restrict__ fgL, const float* __restrict__ fbL,
    const float* __restrict__ fgR, const float* __restrict__ fbR,
    const float* __restrict__ fwL, const float* __restrict__ fcbL,
    const float* __restrict__ fwR, const float* __restrict__ fcbR,
    float* __restrict__ out)
{
  const int bx = blockIdx.x;
  const int b = bx & 7, arm = bx >> 3;
  const int tid = threadIdx.x;
  const int p = tid >> 3, k8 = tid & 7;
  const float* xr1 = xp + ((long)arm * 64 + b * 8 + p) * DD;
  const float* xr2 = xr1 + 2 * BLK;

  float s = 0.f, ss = 0.f;
  for (int k = k8 * 64; k < k8 * 64 + 64; k += 4) {
    float4 v = *reinterpret_cast<const float4*>(xr1 + k);
    float4 u = *reinterpret_cast<const float4*>(xr2 + k);
    float a0 = fmaxf(v.x + u.x, 0.f), a1 = fmaxf(v.y + u.y, 0.f);
    float a2 = fmaxf(v.z + u.z, 0.f), a3 = fmaxf(v.w + u.w, 0.f);
    s  += a0 + a1 + a2 + a3;
    ss += a0 * a0 + a1 * a1 + a2 * a2 + a3 * a3;
  }
  s += __shfl_xor(s, 1); ss += __shfl_xor(ss, 1);
  s += __shfl_xor(s, 2); ss += __shfl_xor(ss, 2);
  s += __shfl_xor(s, 4); ss += __shfl_xor(ss, 4);
  const float mu = s * (1.f / 512.f);
  const float var = ss * (1.f / 512.f) - mu * mu;
  const float rstd = rsqrtf(var + 1e-5f);

  const float* g   = arm ? fgR : fgL;
  const float* bb  = arm ? fbR : fbL;
  const float* fw  = arm ? fwR : fwL;
  const float* fcb = arm ? fcbR : fcbL;
  const int j = k8;
  if (j < 7) {
    float acc = 0.f;
    for (int k = 0; k < 512; ++k) {
      const float xv = fmaxf(xr1[k] + xr2[k], 0.f);
      const float xn = (xv - mu) * rstd * g[k] + bb[k];
      acc += xn * fw[k * 7 + j];
    }
    out[((long)(b * 8) + p) * 14 + arm * 7 + j] = acc + fcb[j];
  }
}

// Init: zero xp partials, RoPE tables, barrier counter
__global__ void k_init(float* __restrict__ xp, float* __restrict__ ropeC,
                       float* __restrict__ ropeS, unsigned int* __restrict__ cnt)
{
  const int t = blockIdx.x * 256 + threadIdx.x;
  if (t == 0) *cnt = 0u;
  if (t < 4 * BLK) xp[t] = 0.f;
  if (t < 512) {
    const int p = t >> 6, d = t & 63;
    const float inv = expf(-(float)(d & 31) * (9.210340371976184f / 32.f));
    const float ang = (float)p * inv;
    ropeC[t] = cosf(ang);
    ropeS[t] = sinf(ang);
  }
}

extern "C" void kernel_launch(void* const* d_in, const int* in_sizes, int n_in,
                              void* d_out, int out_size, void* d_ws, size_t ws_size,
                              hipStream_t stream)
{
  (void)in_sizes; (void)n_in; (void)out_size;

  const float* ahs  = (const float*)d_in[0];
  const float* WL   = (const float*)d_in[1];
  const float* bL   = (const float*)d_in[2];
  const float* lngL = (const float*)d_in[3];
  const float* lnbL = (const float*)d_in[4];
  const float* WR   = (const float*)d_in[5];
  const float* bR   = (const float*)d_in[6];
  const float* lngR = (const float*)d_in[7];
  const float* lnbR = (const float*)d_in[8];
  const float* gating = (const float*)d_in[9];
  const float* fgL  = (const float*)d_in[10];
  const float* fbL  = (const float*)d_in[11];
  const float* fgR  = (const float*)d_in[12];
  const float* fbR  = (const float*)d_in[13];
  const float* fwL  = (const float*)d_in[14];
  const float* fcbL = (const float*)d_in[15];
  const float* fwR  = (const float*)d_in[16];
  const float* fcbR = (const float*)d_in[17];
  float* out = (float*)d_out;

  char* ws = (char*)d_ws;
  size_t off = 0;
  unsigned int* cnt = (unsigned int*)(ws + off); off += 256;
  float* ropeC = (float*)(ws + off); off += 512 * 4;
  float* ropeS = (float*)(ws + off); off += 512 * 4;
  float* xp    = (float*)(ws + off); off += (size_t)4 * BLK * 4;   // [kh][arm]
  float* qkvb  = (float*)(ws + off); off += (size_t)10 * BLK * 4;
  float* attno = (float*)(ws + off); off += (size_t)2 * BLK * 4;
  float* yp    = (float*)(ws + off); off += (size_t)4 * BLK * 4;   // [kh][arm]
  float* kvt   = (float*)(ws + off); off += (size_t)NBLK * 4 * 512 * DD * 4;
  float* kva   = (float*)(ws + off); off += (size_t)NBLK * 4 * 64 * DD * 4;
  unsigned short* Wt = (unsigned short*)(ws + off);
  const size_t need = off + (size_t)NBLK * 2 * 7 * WT_SLOT * 2;

  const bool useT = (ws_size >= need);
  const int wtC = useT ? 336 * 32 : 0;

  k_init<<<dim3(512), dim3(256), 0, stream>>>(xp, ropeC, ropeS, cnt);
  k_pre<<<dim3(2304 + wtC), dim3(256), 0, stream>>>(
      ahs, WL, WR, bL, bR, kvt, kva, Wt, wtC);

  if (useT) {
    k_fused<<<dim3(FNWG), dim3(512), 0, stream>>>(
        xp, qkvb, attno, yp, kvt, kva, Wt, bL, bR,
        lngL, lnbL, lngR, lnbR, gating, ropeC, ropeS,
        fgL, fbL, fgR, fbR, fwL, fcbL, fwR, fcbR, out, cnt);
  } else {
    for (int nb = 0; nb < NBLK; ++nb) {
      k_qkv_g<<<dim3(80),  dim3(256), 0, stream>>>(xp, WL, WR, bL, bR, qkvb, nb);
      k_attn<<<dim3(128), dim3(512), 0, stream>>>(qkvb, kvt, kva, gating, ropeC, ropeS, attno, nb);
      k_proj_g<<<dim3(16),  dim3(256), 0, stream>>>(attno, WL, WR, bL, bR, xp, yp, nb);
      k_ffn_g<<<dim3(16),  dim3(256), 0, stream>>>(yp, WL, WR, bL, bR, lngL, lnbL, lngR, lnbR, xp, nb);
    }
    k_final<<<dim3(16), dim3(64), 0, stream>>>(xp, fgL, fbL, fgR, fbR, fwL, fcbL, fwR, fcbR, out);
  }
}

// Round 8
// 3012.932 us; speedup vs baseline: 2.4736x; 1.0226x over previous
//
#include <hip/hip_runtime.h>

#define DD 512
#define NBLK 24
#define BLK (64 * DD)            // one 64-row arm block (floats)
#define WT_SLOT 524288           // shorts per transposed matrix (512*512*2)
#define FNWG 160                 // fused-kernel grid (= qkv phase width)

typedef short s16x8 __attribute__((ext_vector_type(8)));
typedef float f32x4 __attribute__((ext_vector_type(4)));

union FragU { s16x8 s; __bf16 h[8]; };

__device__ __forceinline__ f32x4 mfma16(s16x8 a, s16x8 b, f32x4 c) {
  return __builtin_amdgcn_mfma_f32_16x16x32_bf16(a, b, c, 0, 0, 0);
}

__device__ __forceinline__ void bsplit(float v, __bf16& hi, __bf16& lo) {
  hi = (__bf16)v;
  lo = (__bf16)(v - (float)hi);
}

// Device-scope barrier (round-5 verified protocol):
//   arrive RELEASE add; spin RELAXED (no invalidate storm); depart one ACQUIRE.
__device__ __forceinline__ void gbar(unsigned int* cnt, unsigned int target) {
  __syncthreads();
  if (threadIdx.x == 0) {
    __hip_atomic_fetch_add(cnt, 1u, __ATOMIC_RELEASE, __HIP_MEMORY_SCOPE_AGENT);
    while (__hip_atomic_load(cnt, __ATOMIC_RELAXED, __HIP_MEMORY_SCOPE_AGENT) < target)
      __builtin_amdgcn_s_sleep(16);
    (void)__hip_atomic_load(cnt, __ATOMIC_ACQUIRE, __HIP_MEMORY_SCOPE_AGENT);
  }
  __syncthreads();
}

// Cache-warming touch loads. Values discarded (kept live via empty asm,
// rule #17) — cannot affect correctness. 512-thread cooperative.
__device__ __forceinline__ void touchW(const unsigned short* base, int nShorts) {
  int acc = 0;
  for (int o = threadIdx.x * 8; o < nShorts; o += 512 * 8) {
    s16x8 v = *reinterpret_cast<const s16x8*>(base + o);
    acc ^= v[0] ^ v[1] ^ v[2] ^ v[3] ^ v[4] ^ v[5] ^ v[6] ^ v[7];
  }
  asm volatile("" :: "v"(acc));
}
__device__ __forceinline__ void touchF(const float* base, int nFloats) {
  float acc = 0.f;
  for (int o = threadIdx.x * 4; o < nFloats; o += 512 * 4) {
    float4 v = *reinterpret_cast<const float4*>(base + o);
    acc += v.x + v.y + v.z + v.w;
  }
  asm volatile("" :: "v"(acc));
}

__constant__ int c_wmap[7] = {0, 1, 2, 7, 8, 9, 10};

// ---------------------------------------------------------------------------
// Gather GEMM core (k_pre's p1a range + ws-too-small fallback path)
// ---------------------------------------------------------------------------
template<int AMODE, bool RESID>
__device__ __forceinline__ void gemm64_core(
    const float* __restrict__ Abase, int rshift, long sOuter,
    const float* __restrict__ Wf,
    const float* __restrict__ bias,
    const float* __restrict__ lng, const float* __restrict__ lnb,
    const float* __restrict__ resid,
    float* __restrict__ outF,
    int n0)
{
  const int tid  = threadIdx.x;
  const int wave = tid >> 6;
  const int lane = tid & 63;
  const int l15  = lane & 15;
  const int lq   = lane >> 4;

  const int rowA = wave * 16 + l15;
  const float* Arow = Abase + (long)(rowA >> rshift) * sOuter
                            + (long)(rowA & ((1 << rshift) - 1)) * DD;

  float mu = 0.f, rstd = 0.f;
  if constexpr (AMODE == 2) {
    float s = 0.f, ss = 0.f;
    const float* p = Arow + lq * 128;
    #pragma unroll
    for (int k = 0; k < 128; k += 4) {
      float4 v = *reinterpret_cast<const float4*>(p + k);
      s  += v.x + v.y + v.z + v.w;
      ss += v.x * v.x + v.y * v.y + v.z * v.z + v.w * v.w;
    }
    s += __shfl_xor(s, 16); ss += __shfl_xor(ss, 16);
    s += __shfl_xor(s, 32); ss += __shfl_xor(ss, 32);
    mu = s * (1.f / 512.f);
    float var = ss * (1.f / 512.f) - mu * mu;
    rstd = rsqrtf(var + 1e-5f);
  }

  f32x4 acc[4] = {};

  for (int ks = 0; ks < 16; ++ks) {
    const int k0 = ks * 32 + lq * 8;
    FragU ahi, alo;
    {
      float4 v0 = *reinterpret_cast<const float4*>(Arow + k0);
      float4 v1 = *reinterpret_cast<const float4*>(Arow + k0 + 4);
      float t0[8] = {v0.x, v0.y, v0.z, v0.w, v1.x, v1.y, v1.z, v1.w};
      if constexpr (AMODE == 2) {
        float4 g0 = *reinterpret_cast<const float4*>(lng + k0);
        float4 g1 = *reinterpret_cast<const float4*>(lng + k0 + 4);
        float4 c0 = *reinterpret_cast<const float4*>(lnb + k0);
        float4 c1 = *reinterpret_cast<const float4*>(lnb + k0 + 4);
        float gg[8] = {g0.x, g0.y, g0.z, g0.w, g1.x, g1.y, g1.z, g1.w};
        float cc[8] = {c0.x, c0.y, c0.z, c0.w, c1.x, c1.y, c1.z, c1.w};
        #pragma unroll
        for (int e = 0; e < 8; ++e) {
          float v = (t0[e] - mu) * rstd * gg[e] + cc[e];
          bsplit(v, ahi.h[e], alo.h[e]);
        }
      } else {
        #pragma unroll
        for (int e = 0; e < 8; ++e) {
          float v = t0[e];
          if constexpr (AMODE == 1) v = fmaxf(v, 0.f);
          bsplit(v, ahi.h[e], alo.h[e]);
        }
      }
    }
    const float* wp = Wf + (long)k0 * DD + n0 + l15;
    #pragma unroll
    for (int j = 0; j < 4; ++j) {
      FragU bhi, blo;
      #pragma unroll
      for (int e = 0; e < 8; ++e) {
        float w = wp[(long)e * DD + j * 16];
        bsplit(w, bhi.h[e], blo.h[e]);
      }
      acc[j] = mfma16(ahi.s, bhi.s, acc[j]);
      acc[j] = mfma16(ahi.s, blo.s, acc[j]);
      acc[j] = mfma16(alo.s, bhi.s, acc[j]);
    }
  }

  const int mbase = wave * 16 + lq * 4;
  #pragma unroll
  for (int j = 0; j < 4; ++j) {
    const int n = n0 + j * 16 + l15;
    const float bv = bias[n];
    #pragma unroll
    for (int r = 0; r < 4; ++r) {
      const int m = mbase + r;
      float v = acc[j][r] + bv;
      if constexpr (RESID) v += fmaxf(resid[(long)m * DD + n], 0.f);
      outF[(long)m * DD + n] = v;
    }
  }
}

// ---------------------------------------------------------------------------
// Transposed-weight core, 512 threads (8 waves): 64 rows x 32 cols tile.
// EXACT round-5 passing version (runtime ks loop, no manual prefetch).
// ---------------------------------------------------------------------------
template<int AMODE, bool A2P>
__device__ __forceinline__ void gemmT512(
    const float* __restrict__ A1, const float* __restrict__ A2,
    const unsigned short* __restrict__ Wt,   // slot base
    const float* __restrict__ bias, int addBias,
    const float* __restrict__ lng, const float* __restrict__ lnb,
    const float* __restrict__ r1, const float* __restrict__ r2,
    float* __restrict__ outF, int n0, int ks0, int ks1)
{
  const int tid  = threadIdx.x;
  const int wave = tid >> 6;
  const int mq   = wave & 3;
  const int nh   = wave >> 2;
  const int lane = tid & 63;
  const int l15  = lane & 15;
  const int lq   = lane >> 4;

  const int rowA = mq * 16 + l15;
  const float* A1row = A1 + (long)rowA * DD;
  const float* A2row = A2P ? (A2 + (long)rowA * DD) : nullptr;

  float mu = 0.f, rstd = 0.f;
  if constexpr (AMODE == 2) {
    float s = 0.f, ss = 0.f;
    const float* p1 = A1row + lq * 128;
    const float* p2 = A2P ? (A2row + lq * 128) : nullptr;
    #pragma unroll
    for (int k = 0; k < 128; k += 4) {
      float4 v = *reinterpret_cast<const float4*>(p1 + k);
      float vx = v.x, vy = v.y, vz = v.z, vw = v.w;
      if constexpr (A2P) {
        float4 u = *reinterpret_cast<const float4*>(p2 + k);
        vx += u.x; vy += u.y; vz += u.z; vw += u.w;
      }
      s  += vx + vy + vz + vw;
      ss += vx * vx + vy * vy + vz * vz + vw * vw;
    }
    s += __shfl_xor(s, 16); ss += __shfl_xor(ss, 16);
    s += __shfl_xor(s, 32); ss += __shfl_xor(ss, 32);
    mu = s * (1.f / 512.f);
    float var = ss * (1.f / 512.f) - mu * mu;
    rstd = rsqrtf(var + 1e-5f);
  }

  f32x4 acc = {};
  const long ngBase = (long)((n0 + nh * 16) >> 4) * 64;

  for (int ks = ks0; ks < ks1; ++ks) {
    const int k0 = ks * 32 + lq * 8;
    FragU ahi, alo;
    {
      float4 v0 = *reinterpret_cast<const float4*>(A1row + k0);
      float4 v1 = *reinterpret_cast<const float4*>(A1row + k0 + 4);
      float t0[8] = {v0.x, v0.y, v0.z, v0.w, v1.x, v1.y, v1.z, v1.w};
      if constexpr (A2P) {
        float4 u0 = *reinterpret_cast<const float4*>(A2row + k0);
        float4 u1 = *reinterpret_cast<const float4*>(A2row + k0 + 4);
        t0[0] += u0.x; t0[1] += u0.y; t0[2] += u0.z; t0[3] += u0.w;
        t0[4] += u1.x; t0[5] += u1.y; t0[6] += u1.z; t0[7] += u1.w;
      }
      if constexpr (AMODE == 2) {
        float4 g0 = *reinterpret_cast<const float4*>(lng + k0);
        float4 g1 = *reinterpret_cast<const float4*>(lng + k0 + 4);
        float4 c0 = *reinterpret_cast<const float4*>(lnb + k0);
        float4 c1 = *reinterpret_cast<const float4*>(lnb + k0 + 4);
        float gg[8] = {g0.x, g0.y, g0.z, g0.w, g1.x, g1.y, g1.z, g1.w};
        float cc[8] = {c0.x, c0.y, c0.z, c0.w, c1.x, c1.y, c1.z, c1.w};
        #pragma unroll
        for (int e = 0; e < 8; ++e) {
          float v = (t0[e] - mu) * rstd * gg[e] + cc[e];
          bsplit(v, ahi.h[e], alo.h[e]);
        }
      } else {
        #pragma unroll
        for (int e = 0; e < 8; ++e) {
          float v = t0[e];
          if constexpr (AMODE == 1) v = fmaxf(v, 0.f);
          bsplit(v, ahi.h[e], alo.h[e]);
        }
      }
    }
    const unsigned short* wp = Wt + ((ngBase + (ks * 4 + lq)) * 16 + l15) * 16;
    s16x8 bhi = *reinterpret_cast<const s16x8*>(wp);
    s16x8 blo = *reinterpret_cast<const s16x8*>(wp + 8);
    acc = mfma16(ahi.s, bhi, acc);
    acc = mfma16(ahi.s, blo, acc);
    acc = mfma16(alo.s, bhi, acc);
  }

  const int mbase = mq * 16 + lq * 4;
  const int n = n0 + nh * 16 + l15;
  const float bv = addBias ? bias[n] : 0.f;
  #pragma unroll
  for (int r = 0; r < 4; ++r) {
    const int m = mbase + r;
    float v = acc[r] + bv;
    if (r1) {
      float rv = r1[(long)m * DD + n];
      if (r2) rv += r2[(long)m * DD + n];
      v += fmaxf(rv, 0.f);
    }
    outF[(long)m * DD + n] = v;
  }
}

#define LDSW 40

// ---------------------------------------------------------------------------
// k_pre: merged phase-0/1 (unchanged, passing since round 5). wg ranges:
//   [0,1536) p1t kt/vt; [1536,1536+wtC) weight transpose; rest p1a ka/va.
// ---------------------------------------------------------------------------
__global__ __launch_bounds__(256) void k_pre(
    const float* __restrict__ ahs,
    const float* __restrict__ WL, const float* __restrict__ WR,
    const float* __restrict__ bL, const float* __restrict__ bR,
    float* __restrict__ kvt, float* __restrict__ kva,
    unsigned short* __restrict__ Wt, int wtC)
{
  const int bx = blockIdx.x;

  if (bx < 1536) {
    __shared__ __align__(16) unsigned short Ab[2][64 * LDSW];
    __shared__ __align__(16) unsigned short Wb[4][2][64 * LDSW];

    const int ntile = bx & 7, mtile = (bx >> 3) & 7, nb = bx >> 6;
    const int n0 = ntile * 64;

    const float* Abase = ahs + (long)(mtile * 25 + nb + 1) * 80 * DD;
    const float* Wp[4];
    const float* bp[4];
    #pragma unroll
    for (int o = 0; o < 4; ++o) {
      const int arm = o >> 1, kv = o & 1;
      Wp[o] = (arm ? WR : WL) + (long)(nb * 11 + 3 + kv) * DD * DD;
      bp[o] = (arm ? bR : bL) + (long)(nb * 11 + 3 + kv) * DD;
    }

    const int tid  = threadIdx.x;
    const int srow = tid >> 2;
    const int skq  = (tid & 3) * 8;
    const int wave = tid >> 6, lane = tid & 63, l15 = lane & 15, lq = lane >> 4;

    f32x4 acc[4][4] = {};
    float aR[8];
    float wRg[4][8];

    auto loadStage = [&](int kbase) {
      const float* ap = Abase + (long)srow * DD + kbase + skq;
      float4 v0 = *reinterpret_cast<const float4*>(ap);
      float4 v1 = *reinterpret_cast<const float4*>(ap + 4);
      aR[0] = v0.x; aR[1] = v0.y; aR[2] = v0.z; aR[3] = v0.w;
      aR[4] = v1.x; aR[5] = v1.y; aR[6] = v1.z; aR[7] = v1.w;
      #pragma unroll
      for (int o = 0; o < 4; ++o) {
        #pragma unroll
        for (int e = 0; e < 8; ++e)
          wRg[o][e] = Wp[o][(long)(kbase + skq + e) * DD + n0 + srow];
      }
    };

    loadStage(0);
    for (int s = 0; s < 16; ++s) {
      __syncthreads();
      {
        FragU uh, ul;
        #pragma unroll
        for (int e = 0; e < 8; ++e) bsplit(aR[e], uh.h[e], ul.h[e]);
        *reinterpret_cast<s16x8*>(&Ab[0][srow * LDSW + skq]) = uh.s;
        *reinterpret_cast<s16x8*>(&Ab[1][srow * LDSW + skq]) = ul.s;
        #pragma unroll
        for (int o = 0; o < 4; ++o) {
          FragU wh, wl;
          #pragma unroll
          for (int e = 0; e < 8; ++e) bsplit(wRg[o][e], wh.h[e], wl.h[e]);
          *reinterpret_cast<s16x8*>(&Wb[o][0][srow * LDSW + skq]) = wh.s;
          *reinterpret_cast<s16x8*>(&Wb[o][1][srow * LDSW + skq]) = wl.s;
        }
      }
      __syncthreads();
      if (s < 15) loadStage((s + 1) * 32);
      s16x8 ahi = *reinterpret_cast<const s16x8*>(&Ab[0][(wave * 16 + l15) * LDSW + lq * 8]);
      s16x8 alo = *reinterpret_cast<const s16x8*>(&Ab[1][(wave * 16 + l15) * LDSW + lq * 8]);
      #pragma unroll
      for (int o = 0; o < 4; ++o) {
        #pragma unroll
        for (int j = 0; j < 4; ++j) {
          s16x8 bhi = *reinterpret_cast<const s16x8*>(&Wb[o][0][(j * 16 + l15) * LDSW + lq * 8]);
          s16x8 blo = *reinterpret_cast<const s16x8*>(&Wb[o][1][(j * 16 + l15) * LDSW + lq * 8]);
          acc[o][j] = mfma16(ahi, bhi, acc[o][j]);
          acc[o][j] = mfma16(ahi, blo, acc[o][j]);
          acc[o][j] = mfma16(alo, bhi, acc[o][j]);
        }
      }
    }

    const int mbase = mtile * 64 + wave * 16 + lq * 4;
    #pragma unroll
    for (int o = 0; o < 4; ++o) {
      float* outb = kvt + (long)(nb * 4 + o) * 512 * DD;
      #pragma unroll
      for (int j = 0; j < 4; ++j) {
        const int n = n0 + j * 16 + l15;
        const float bv = bp[o][n];
        #pragma unroll
        for (int r = 0; r < 4; ++r)
          outb[(long)(mbase + r) * DD + n] = acc[o][j][r] + bv;
      }
    }
  } else if (bx < 1536 + wtC) {
    const int wbx = bx - 1536;
    const int ng = wbx & 31, slot = wbx >> 5;
    const int wi7 = slot % 7, nb2 = slot / 7;
    const int arm = nb2 & 1, nb = nb2 >> 1;
    const float* Wsrc = (arm ? WR : WL) + (long)(nb * 11 + c_wmap[wi7]) * DD * DD;

    const int t = threadIdx.x;
    const int k8 = t >> 2, lbase = (t & 3) * 4;

    unsigned short hi[4][8], lo[4][8];
    #pragma unroll
    for (int e = 0; e < 8; ++e) {
      float4 v = *reinterpret_cast<const float4*>(
          Wsrc + (long)(k8 * 8 + e) * DD + ng * 16 + lbase);
      float vv[4] = {v.x, v.y, v.z, v.w};
      #pragma unroll
      for (int c = 0; c < 4; ++c) {
        __bf16 h, l;
        bsplit(vv[c], h, l);
        union { __bf16 b; unsigned short u; } ch, cl; ch.b = h; cl.b = l;
        hi[c][e] = ch.u; lo[c][e] = cl.u;
      }
    }
    unsigned short* dst = Wt + (long)slot * WT_SLOT
                        + ((long)(ng * 64 + k8) * 16 + lbase) * 16;
    #pragma unroll
    for (int c = 0; c < 4; ++c) {
      s16x8 a, b;
      #pragma unroll
      for (int e = 0; e < 8; ++e) { ((short*)&a)[e] = hi[c][e]; ((short*)&b)[e] = lo[c][e]; }
      *reinterpret_cast<s16x8*>(dst + c * 16)     = a;
      *reinterpret_cast<s16x8*>(dst + c * 16 + 8) = b;
    }
  } else {
    const int pbx = bx - 1536 - wtC;
    const int ntile = pbx & 7, kv = (pbx >> 3) & 1, arm = (pbx >> 4) & 1, nb = pbx >> 5;
    const float* Abase = ahs + ((long)(nb + 1) * 80 + 64 + arm * 8) * DD;
    const float* W    = (arm ? WR : WL) + (long)(nb * 11 + 5 + kv) * DD * DD;
    const float* bias = (arm ? bR : bL) + (long)(nb * 11 + 5 + kv) * DD;
    float* out = kva + (long)(nb * 4 + arm * 2 + kv) * 64 * DD;
    gemm64_core<0, false>(Abase, 3, (long)25 * 80 * DD, W, bias,
                          nullptr, nullptr, nullptr, out, ntile * 64);
  }
}

// ---------------------------------------------------------------------------
// FUSED sequential scan: 160 wgs x 512 threads — EXACT round-5 compute path.
// Only addition: idle-wg cache-warming touches (discarded loads).
// ---------------------------------------------------------------------------
__global__ __launch_bounds__(512, 4) void k_fused(
    float* __restrict__ xp, float* __restrict__ qkvb,
    float* __restrict__ attno, float* __restrict__ yp,
    const float* __restrict__ kvt, const float* __restrict__ kva,
    const unsigned short* __restrict__ Wt,
    const float* __restrict__ bL, const float* __restrict__ bR,
    const float* __restrict__ lngL, const float* __restrict__ lnbL,
    const float* __restrict__ lngR, const float* __restrict__ lnbR,
    const float* __restrict__ gating,
    const float* __restrict__ ropeC, const float* __restrict__ ropeS,
    const float* __restrict__ fgL, const float* __restrict__ fbL,
    const float* __restrict__ fgR, const float* __restrict__ fbR,
    const float* __restrict__ fwL, const float* __restrict__ fcbL,
    const float* __restrict__ fwR, const float* __restrict__ fcbR,
    float* __restrict__ out, unsigned int* __restrict__ cnt)
{
  __shared__ float kb[88 * 65];
  __shared__ float vb[88 * 65];
  __shared__ float qb[8 * 65];
  __shared__ float pb[8 * 89];

  const int wg  = blockIdx.x;
  const int tid = threadIdx.x;
  unsigned int bi = 0;

  for (int nb = 0; nb < NBLK; ++nb) {
    // ---------------- QKV: 160 wgs = (arm, wi, nt) ----------------
    {
      const int arm = wg / 80;
      const int rem = wg - arm * 80;
      const int wi = rem >> 4, nt = rem & 15;
      const int sel = (wi < 3) ? arm : (1 - arm);
      gemmT512<1, true>(
          xp + (long)sel * BLK, xp + (long)(2 + sel) * BLK,
          Wt + (((long)nb * 2 + arm) * 7 + wi) * WT_SLOT,
          (arm ? bR : bL) + ((long)nb * 11 + c_wmap[wi]) * DD, 1,
          nullptr, nullptr, nullptr, nullptr,
          qkvb + ((long)arm * 5 + wi) * BLK, nt * 32, 0, 16);
    }
    gbar(cnt, ++bi * FNWG);

    // ---------------- ATTN: 128 wgs (arm,b,h) ----------------
    if (wg < 128) {
      const int h = wg & 7, b = (wg >> 3) & 7, arm = wg >> 6;
      const float g = tanhf(gating[nb]);

      {
        const int p = tid >> 6, d = tid & 63;
        const float* qrow = qkvb + ((long)(arm * 5 + 0) * 64 + b * 8 + p) * DD + h * 64;
        float v = qrow[d], vp = qrow[d ^ 1];
        float c = ropeC[p * 64 + d], s = ropeS[p * 64 + d];
        qb[p * 65 + d] = v * c + ((d & 1) ? vp : -vp) * s;
      }
      for (int idx = tid; idx < 88 * 64; idx += 512) {
        const int j = idx >> 6, d = idx & 63;
        float kvval, vvval;
        if (j < 8) {
          const float* krow = qkvb + ((long)(arm * 5 + 1) * 64 + b * 8 + j) * DD + h * 64;
          float v = krow[d], vp = krow[d ^ 1];
          float c = ropeC[j * 64 + d], s = ropeS[j * 64 + d];
          kvval = v * c + ((d & 1) ? vp : -vp) * s;
          vvval = qkvb[((long)(arm * 5 + 2) * 64 + b * 8 + j) * DD + h * 64 + d];
        } else if (j < 16) {
          const int t = j - 8;
          kvval = kva[((long)(nb * 4 + arm * 2 + 0) * 64 + b * 8 + t) * DD + h * 64 + d];
          vvval = kva[((long)(nb * 4 + arm * 2 + 1) * 64 + b * 8 + t) * DD + h * 64 + d];
        } else if (j < 80) {
          const int t = j - 16;
          kvval = g * kvt[((long)(nb * 4 + arm * 2 + 0) * 512 + b * 64 + t) * DD + h * 64 + d];
          vvval = kvt[((long)(nb * 4 + arm * 2 + 1) * 512 + b * 64 + t) * DD + h * 64 + d];
        } else {
          const int t = j - 80;
          const float* krow = qkvb + ((long)(arm * 5 + 3) * 64 + b * 8 + t) * DD + h * 64;
          float v = krow[d], vp = krow[d ^ 1];
          float c = ropeC[t * 64 + d], s = ropeS[t * 64 + d];
          kvval = v * c + ((d & 1) ? vp : -vp) * s;
          vvval = qkvb[((long)(arm * 5 + 4) * 64 + b * 8 + t) * DD + h * 64 + d];
        }
        kb[j * 65 + d] = kvval;
        vb[j * 65 + d] = vvval;
      }
      __syncthreads();

      const int p = tid >> 6, lane = tid & 63;
      float s0 = 0.f, s1 = 0.f;
      const int j2 = 64 + ((lane < 24) ? lane : 0);
      #pragma unroll 8
      for (int d = 0; d < 64; ++d) {
        const float q = qb[p * 65 + d];
        s0 += q * kb[lane * 65 + d];
        s1 += q * kb[j2 * 65 + d];
      }
      s0 *= 0.125f; s1 *= 0.125f;
      float m = (lane < 24) ? fmaxf(s0, s1) : s0;
      #pragma unroll
      for (int off = 1; off < 64; off <<= 1) m = fmaxf(m, __shfl_xor(m, off));
      const float e0 = __expf(s0 - m);
      const float e1 = (lane < 24) ? __expf(s1 - m) : 0.f;
      float sum = e0 + e1;
      #pragma unroll
      for (int off = 1; off < 64; off <<= 1) sum += __shfl_xor(sum, off);
      const float inv = 1.f / sum;
      pb[p * 89 + lane] = e0 * inv;
      if (lane < 24) pb[p * 89 + 64 + lane] = e1 * inv;
      __syncthreads();

      float acc = 0.f;
      #pragma unroll 8
      for (int j = 0; j < 88; ++j) acc += pb[p * 89 + j] * vb[j * 65 + lane];
      attno[((long)arm * 64 + b * 8 + p) * DD + h * 64 + lane] = acc;
    } else {
      // wgs 128-159: warm proj+ffn weights of CURRENT block (4 MB / 32 wgs)
      const int idx = wg - 128;            // 0..31
      const int arm = idx >> 4;            // 0..1
      const int mi  = (idx >> 3) & 1;      // 0=proj(5), 1=ffn(6)
      const int part = idx & 7;            // 0..7
      touchW(Wt + (((long)nb * 2 + arm) * 7 + 5 + mi) * WT_SLOT
                + (long)part * (WT_SLOT / 8), WT_SLOT / 8);
    }
    gbar(cnt, ++bi * FNWG);

    // ---------------- PROJ: 64 wgs (arm,kh,nt), K-split 2 ----------------
    if (wg < 64) {
      const int arm = wg >> 5, kh = (wg >> 4) & 1, nt = wg & 15;
      gemmT512<0, false>(
          attno + (long)arm * BLK, nullptr,
          Wt + (((long)nb * 2 + arm) * 7 + 5) * WT_SLOT,
          (arm ? bR : bL) + ((long)nb * 11 + 9) * DD, kh == 0,
          nullptr, nullptr,
          kh == 0 ? xp + (long)arm * BLK : nullptr,
          kh == 0 ? xp + (long)(2 + arm) * BLK : nullptr,
          yp + (long)(kh * 2 + arm) * BLK, nt * 32, kh * 8, kh * 8 + 8);
    } else if (nb + 1 < NBLK) {
      // wgs 64-159: warm their OWN next-block QKV weight tile (64 KB each)
      const int arm = wg / 80;
      const int rem = wg - arm * 80;
      const int wi = rem >> 4, nt = rem & 15;
      touchW(Wt + (((long)(nb + 1) * 2 + arm) * 7 + wi) * WT_SLOT
                + (long)(nt * 2) * 64 * 256, 2 * 64 * 256);
    }
    gbar(cnt, ++bi * FNWG);

    // ---------------- FFN: 64 wgs ----------------
    if (wg < 64) {
      const int arm = wg >> 5, kh = (wg >> 4) & 1, nt = wg & 15;
      gemmT512<2, true>(
          yp + (long)arm * BLK, yp + (long)(2 + arm) * BLK,
          Wt + (((long)nb * 2 + arm) * 7 + 6) * WT_SLOT,
          (arm ? bR : bL) + ((long)nb * 11 + 10) * DD, kh == 0,
          (arm ? lngR : lngL) + (long)nb * DD, (arm ? lnbR : lnbL) + (long)nb * DD,
          nullptr, nullptr,
          xp + (long)(kh * 2 + arm) * BLK, nt * 32, kh * 8, kh * 8 + 8);
    } else if (nb + 1 < NBLK) {
      const int idx = wg - 64;             // 0..95
      if (idx < 64) {
        // warm next-block QKV tiles of wgs 0..63 (arm0, wi 0..3)
        const int wi = idx >> 4, nt = idx & 15;
        touchW(Wt + (((long)(nb + 1) * 2 + 0) * 7 + wi) * WT_SLOT
                  + (long)(nt * 2) * 64 * 256, 2 * 64 * 256);
      } else {
        // wgs 128-159: warm next-block kvt (4 MB / 32 wgs)
        const int j = idx - 64;            // 0..31
        const int o = j >> 3, part = j & 7;
        touchF(kvt + ((long)((nb + 1) * 4 + o) * 512) * DD
                   + (long)part * (512 * DD / 8), 512 * DD / 8);
      }
    }
    gbar(cnt, ++bi * FNWG);
  }

  // ---------------- FINAL head: 16 wgs x 64 threads ----------------
  if (wg < 16 && tid < 64) {
    const int b = wg & 7, arm = wg >> 3;
    const int p = tid >> 3, k8 = tid & 7;
    const float* xr1 = xp + ((long)arm * 64 + b * 8 + p) * DD;
    const float* xr2 = xr1 + 2 * BLK;

    float s = 0.f, ss = 0.f;
    for (int k = k8 * 64; k < k8 * 64 + 64; k += 4) {
      float4 v = *reinterpret_cast<const float4*>(xr1 + k);
      float4 u = *reinterpret_cast<const float4*>(xr2 + k);
      float a0 = fmaxf(v.x + u.x, 0.f), a1 = fmaxf(v.y + u.y, 0.f);
      float a2 = fmaxf(v.z + u.z, 0.f), a3 = fmaxf(v.w + u.w, 0.f);
      s  += a0 + a1 + a2 + a3;
      ss += a0 * a0 + a1 * a1 + a2 * a2 + a3 * a3;
    }
    s += __shfl_xor(s, 1); ss += __shfl_xor(ss, 1);
    s += __shfl_xor(s, 2); ss += __shfl_xor(ss, 2);
    s += __shfl_xor(s, 4); ss += __shfl_xor(ss, 4);
    const float mu = s * (1.f / 512.f);
    const float var = ss * (1.f / 512.f) - mu * mu;
    const float rstd = rsqrtf(var + 1e-5f);

    const float* g   = arm ? fgR : fgL;
    const float* bb  = arm ? fbR : fbL;
    const float* fw  = arm ? fwR : fwL;
    const float* fcb = arm ? fcbR : fcbL;
    const int j = k8;
    if (j < 7) {
      float acc = 0.f;
      for (int k = 0; k < 512; ++k) {
        const float xv = fmaxf(xr1[k] + xr2[k], 0.f);
        const float xn = (xv - mu) * rstd * g[k] + bb[k];
        acc += xn * fw[k * 7 + j];
      }
      out[((long)(b * 8) + p) * 14 + arm * 7 + j] = acc + fcb[j];
    }
  }
}

// ---------------------------------------------------------------------------
// Fallback (gather path) kernels — only used when ws can't hold Wt
// ---------------------------------------------------------------------------
__global__ __launch_bounds__(256) void k_qkv_g(
    const float* __restrict__ x,
    const float* __restrict__ WL, const float* __restrict__ WR,
    const float* __restrict__ bL, const float* __restrict__ bR,
    float* __restrict__ qkv, int nb)
{
  const int bx = blockIdx.x;
  const int arm = bx / 40;
  const int rem = bx - arm * 40;
  const int wi = rem >> 3, ntile = rem & 7;
  const int w = (wi < 3) ? wi : wi + 4;
  const float* A    = x + (long)((wi < 3) ? arm : (1 - arm)) * BLK;
  const float* W    = (arm ? WR : WL) + (long)(nb * 11 + w) * DD * DD;
  const float* bias = (arm ? bR : bL) + (long)(nb * 11 + w) * DD;
  float* out = qkv + (long)(arm * 5 + wi) * BLK;
  gemm64_core<1, false>(A, 6, 0, W, bias, nullptr, nullptr, nullptr,
                        out, ntile * 64);
}

__global__ __launch_bounds__(256) void k_proj_g(
    const float* __restrict__ attno,
    const float* __restrict__ WL, const float* __restrict__ WR,
    const float* __restrict__ bL, const float* __restrict__ bR,
    const float* __restrict__ x, float* __restrict__ y, int nb)
{
  const int bx = blockIdx.x;
  const int arm = bx >> 3, ntile = bx & 7;
  const float* A    = attno + (long)arm * BLK;
  const float* W    = (arm ? WR : WL) + (long)(nb * 11 + 9) * DD * DD;
  const float* bias = (arm ? bR : bL) + (long)(nb * 11 + 9) * DD;
  gemm64_core<0, true>(A, 6, 0, W, bias, nullptr, nullptr,
                       x + (long)arm * BLK, y + (long)arm * BLK, ntile * 64);
}

__global__ __launch_bounds__(256) void k_ffn_g(
    const float* __restrict__ y,
    const float* __restrict__ WL, const float* __restrict__ WR,
    const float* __restrict__ bL, const float* __restrict__ bR,
    const float* __restrict__ lngL, const float* __restrict__ lnbL,
    const float* __restrict__ lngR, const float* __restrict__ lnbR,
    float* __restrict__ x, int nb)
{
  const int bx = blockIdx.x;
  const int arm = bx >> 3, ntile = bx & 7;
  const float* A    = y + (long)arm * BLK;
  const float* W    = (arm ? WR : WL) + (long)(nb * 11 + 10) * DD * DD;
  const float* bias = (arm ? bR : bL) + (long)(nb * 11 + 10) * DD;
  const float* g    = (arm ? lngR : lngL) + (long)nb * DD;
  const float* bb   = (arm ? lnbR : lnbL) + (long)nb * DD;
  gemm64_core<2, false>(A, 6, 0, W, bias, g, bb, nullptr,
                        x + (long)arm * BLK, ntile * 64);
}

__global__ __launch_bounds__(512) void k_attn(
    const float* __restrict__ qkv, const float* __restrict__ kvt,
    const float* __restrict__ kva, const float* __restrict__ gating,
    const float* __restrict__ ropeC, const float* __restrict__ ropeS,
    float* __restrict__ attnout, int nb)
{
  __shared__ float kb[88 * 65];
  __shared__ float vb[88 * 65];
  __shared__ float qb[8 * 65];
  __shared__ float pb[8 * 89];

  const int bx = blockIdx.x;
  const int h = bx & 7, b = (bx >> 3) & 7, arm = bx >> 6;
  const int tid = threadIdx.x;
  const float g = tanhf(gating[nb]);

  {
    const int p = tid >> 6, d = tid & 63;
    const float* qrow = qkv + ((long)(arm * 5 + 0) * 64 + b * 8 + p) * DD + h * 64;
    float v = qrow[d], vp = qrow[d ^ 1];
    float c = ropeC[p * 64 + d], s = ropeS[p * 64 + d];
    qb[p * 65 + d] = v * c + ((d & 1) ? vp : -vp) * s;
  }
  for (int idx = tid; idx < 88 * 64; idx += 512) {
    const int j = idx >> 6, d = idx & 63;
    float kvval, vvval;
    if (j < 8) {
      const float* krow = qkv + ((long)(arm * 5 + 1) * 64 + b * 8 + j) * DD + h * 64;
      float v = krow[d], vp = krow[d ^ 1];
      float c = ropeC[j * 64 + d], s = ropeS[j * 64 + d];
      kvval = v * c + ((d & 1) ? vp : -vp) * s;
      vvval = qkv[((long)(arm * 5 + 2) * 64 + b * 8 + j) * DD + h * 64 + d];
    } else if (j < 16) {
      const int t = j - 8;
      kvval = kva[((long)(nb * 4 + arm * 2 + 0) * 64 + b * 8 + t) * DD + h * 64 + d];
      vvval = kva[((long)(nb * 4 + arm * 2 + 1) * 64 + b * 8 + t) * DD + h * 64 + d];
    } else if (j < 80) {
      const int t = j - 16;
      kvval = g * kvt[((long)(nb * 4 + arm * 2 + 0) * 512 + b * 64 + t) * DD + h * 64 + d];
      vvval = kvt[((long)(nb * 4 + arm * 2 + 1) * 512 + b * 64 + t) * DD + h * 64 + d];
    } else {
      const int t = j - 80;
      const float* krow = qkv + ((long)(arm * 5 + 3) * 64 + b * 8 + t) * DD + h * 64;
      float v = krow[d], vp = krow[d ^ 1];
      float c = ropeC[t * 64 + d], s = ropeS[t * 64 + d];
      kvval = v * c + ((d & 1) ? vp : -vp) * s;
      vvval = qkv[((long)(arm * 5 + 4) * 64 + b * 8 + t) * DD + h * 64 + d];
    }
    kb[j * 65 + d] = kvval;
    vb[j * 65 + d] = vvval;
  }
  __syncthreads();

  const int p = tid >> 6, lane = tid & 63;
  float s0 = 0.f, s1 = 0.f;
  const int j2 = 64 + ((lane < 24) ? lane : 0);
  #pragma unroll 8
  for (int d = 0; d < 64; ++d) {
    const float q = qb[p * 65 + d];
    s0 += q * kb[lane * 65 + d];
    s1 += q * kb[j2 * 65 + d];
  }
  s0 *= 0.125f; s1 *= 0.125f;
  float m = (lane < 24) ? fmaxf(s0, s1) : s0;
  #pragma unroll
  for (int off = 1; off < 64; off <<= 1) m = fmaxf(m, __shfl_xor(m, off));
  const float e0 = __expf(s0 - m);
  const float e1 = (lane < 24) ? __expf(s1 - m) : 0.f;
  float sum = e0 + e1;
  #pragma unroll
  for (int off = 1; off < 64; off <<= 1) sum += __shfl_xor(sum, off);
  const float inv = 1.f / sum;
  pb[p * 89 + lane] = e0 * inv;
  if (lane < 24) pb[p * 89 + 64 + lane] = e1 * inv;
  __syncthreads();

  float acc = 0.f;
  #pragma unroll 8
  for (int j = 0; j < 88; ++j) acc += pb[p * 89 + j] * vb[j * 65 + lane];
  attnout[((long)arm * 64 + b * 8 + p) * DD + h * 64 + lane] = acc;
}

__global__ __launch_bounds__(64) void k_final(
    const float* __restrict__ xp,
    const float* __restrict__ fgL, const float* __restrict__ fbL,
    const float* __restrict__ fgR, const float* __restrict__ fbR,
    const float* __restrict__ fwL, const float* __restrict__ fcbL,
    const float* __restrict__ fwR, const float* __restrict__ fcbR,
    float* __restrict__ out)
{
  const int bx = blockIdx.x;
  const int b = bx & 7, arm = bx >> 3;
  const int tid = threadIdx.x;
  const int p = tid >> 3, k8 = tid & 7;
  const float* xr1 = xp + ((long)arm * 64 + b * 8 + p) * DD;
  const float* xr2 = xr1 + 2 * BLK;

  float s = 0.f, ss = 0.f;
  for (int k = k8 * 64; k < k8 * 64 + 64; k += 4) {
    float4 v = *reinterpret_cast<const float4*>(xr1 + k);
    float4 u = *reinterpret_cast<const float4*>(xr2 + k);
    float a0 = fmaxf(v.x + u.x, 0.f), a1 = fmaxf(v.y + u.y, 0.f);
    float a2 = fmaxf(v.z + u.z, 0.f), a3 = fmaxf(v.w + u.w, 0.f);
    s  += a0 + a1 + a2 + a3;
    ss += a0 * a0 + a1 * a1 + a2 * a2 + a3 * a3;
  }
  s += __shfl_xor(s, 1); ss += __shfl_xor(ss, 1);
  s += __shfl_xor(s, 2); ss += __shfl_xor(ss, 2);
  s += __shfl_xor(s, 4); ss += __shfl_xor(ss, 4);
  const float mu = s * (1.f / 512.f);
  const float var = ss * (1.f / 512.f) - mu * mu;
  const float rstd = rsqrtf(var + 1e-5f);

  const float* g   = arm ? fgR : fgL;
  const float* bb  = arm ? fbR : fbL;
  const float* fw  = arm ? fwR : fwL;
  const float* fcb = arm ? fcbR : fcbL;
  const int j = k8;
  if (j < 7) {
    float acc = 0.f;
    for (int k = 0; k < 512; ++k) {
      const float xv = fmaxf(xr1[k] + xr2[k], 0.f);
      const float xn = (xv - mu) * rstd * g[k] + bb[k];
      acc += xn * fw[k * 7 + j];
    }
    out[((long)(b * 8) + p) * 14 + arm * 7 + j] = acc + fcb[j];
  }
}

// Init: zero xp partials, RoPE tables, barrier counter (round-5 version)
__global__ void k_init(float* __restrict__ xp, float* __restrict__ ropeC,
                       float* __restrict__ ropeS, unsigned int* __restrict__ cnt)
{
  const int t = blockIdx.x * 256 + threadIdx.x;
  if (t == 0) *cnt = 0u;
  if (t < 4 * BLK) xp[t] = 0.f;
  if (t < 512) {
    const int p = t >> 6, d = t & 63;
    const float inv = expf(-(float)(d & 31) * (9.210340371976184f / 32.f));
    const float ang = (float)p * inv;
    ropeC[t] = cosf(ang);
    ropeS[t] = sinf(ang);
  }
}

extern "C" void kernel_launch(void* const* d_in, const int* in_sizes, int n_in,
                              void* d_out, int out_size, void* d_ws, size_t ws_size,
                              hipStream_t stream)
{
  (void)in_sizes; (void)n_in; (void)out_size;

  const float* ahs  = (const float*)d_in[0];
  const float* WL   = (const float*)d_in[1];
  const float* bL   = (const float*)d_in[2];
  const float* lngL = (const float*)d_in[3];
  const float* lnbL = (const float*)d_in[4];
  const float* WR   = (const float*)d_in[5];
  const float* bR   = (const float*)d_in[6];
  const float* lngR = (const float*)d_in[7];
  const float* lnbR = (const float*)d_in[8];
  const float* gating = (const float*)d_in[9];
  const float* fgL  = (const float*)d_in[10];
  const float* fbL  = (const float*)d_in[11];
  const float* fgR  = (const float*)d_in[12];
  const float* fbR  = (const float*)d_in[13];
  const float* fwL  = (const float*)d_in[14];
  const float* fcbL = (const float*)d_in[15];
  const float* fwR  = (const float*)d_in[16];
  const float* fcbR = (const float*)d_in[17];
  float* out = (float*)d_out;

  char* ws = (char*)d_ws;
  size_t off = 0;
  unsigned int* cnt = (unsigned int*)(ws + off); off += 256;
  float* ropeC = (float*)(ws + off); off += 512 * 4;
  float* ropeS = (float*)(ws + off); off += 512 * 4;
  float* xp    = (float*)(ws + off); off += (size_t)4 * BLK * 4;    // [kh][arm]
  float* qkvb  = (float*)(ws + off); off += (size_t)10 * BLK * 4;   // [arm*5+wi]
  float* attno = (float*)(ws + off); off += (size_t)2 * BLK * 4;
  float* yp    = (float*)(ws + off); off += (size_t)4 * BLK * 4;    // [kh][arm]
  float* kvt   = (float*)(ws + off); off += (size_t)NBLK * 4 * 512 * DD * 4;
  float* kva   = (float*)(ws + off); off += (size_t)NBLK * 4 * 64 * DD * 4;
  unsigned short* Wt = (unsigned short*)(ws + off);
  const size_t need = off + (size_t)NBLK * 2 * 7 * WT_SLOT * 2;

  const bool useT = (ws_size >= need);
  const int wtC = useT ? 336 * 32 : 0;

  k_init<<<dim3(512), dim3(256), 0, stream>>>(xp, ropeC, ropeS, cnt);
  k_pre<<<dim3(2304 + wtC), dim3(256), 0, stream>>>(
      ahs, WL, WR, bL, bR, kvt, kva, Wt, wtC);

  if (useT) {
    k_fused<<<dim3(FNWG), dim3(512), 0, stream>>>(
        xp, qkvb, attno, yp, kvt, kva, Wt, bL, bR,
        lngL, lnbL, lngR, lnbR, gating, ropeC, ropeS,
        fgL, fbL, fgR, fbR, fwL, fcbL, fwR, fcbR, out, cnt);
  } else {
    for (int nb = 0; nb < NBLK; ++nb) {
      k_qkv_g<<<dim3(80),  dim3(256), 0, stream>>>(xp, WL, WR, bL, bR, qkvb, nb);
      k_attn<<<dim3(128), dim3(512), 0, stream>>>(qkvb, kvt, kva, gating, ropeC, ropeS, attno, nb);
      k_proj_g<<<dim3(16),  dim3(256), 0, stream>>>(attno, WL, WR, bL, bR, xp, yp, nb);
      k_ffn_g<<<dim3(16),  dim3(256), 0, stream>>>(yp, WL, WR, bL, bR, lngL, lnbL, lngR, lnbR, xp, nb);
    }
    k_final<<<dim3(16), dim3(64), 0, stream>>>(xp, fgL, fbL, fgR, fbR, fwL, fcbL, fwR, fcbR, out);
  }
}